// Round 12
// baseline (654.500 us; speedup 1.0000x reference)
//
#include <hip/hip_runtime.h>
#include <cstdint>
#include <cstddef>

typedef __bf16 bf16;
typedef __bf16 bf16x8 __attribute__((ext_vector_type(8)));
typedef __bf16 bf16x4 __attribute__((ext_vector_type(4)));
typedef float floatx4 __attribute__((ext_vector_type(4)));

#define GLD16(gp, lp) __builtin_amdgcn_global_load_lds( \
    (const __attribute__((address_space(1))) void*)(gp), \
    (__attribute__((address_space(3))) void*)(lp), 16, 0, 0)

// ---------------------------------------------------------------------------
// Symmetric augment GEMM: upper-tri 128x128 block pairs of C = R * R^T,
// R [k x n] bf16. Per-(pair,z) slices, no atomics. Slice dtype: bf16 when
// partial sums are exact ints <=256 (L1: 0/1 entries, counts <=~60), else fp32.
// ---------------------------------------------------------------------------
__global__ __launch_bounds__(256) void gemm_sym(
    const bf16* __restrict__ R, bf16* __restrict__ CsBf, float* __restrict__ CsF,
    int n /*lda = K*/, int kIters, int G)
{
  __shared__ __align__(16) bf16 smem[2 * 128 * 32];
  bf16* As = smem;
  bf16* Bs = smem + 128 * 32;

  int rem = blockIdx.x, bm = 0;
  while (rem >= G - bm) { rem -= G - bm; ++bm; }
  const int bn = bm + rem;
  const int m0 = bm * 128, n0 = bn * 128;

  const int t = threadIdx.x;
  const int w = t >> 6, l = t & 63;
  const int wr = w >> 1, wc = w & 1;
  const int lr = l & 15, q = l >> 4;
  const int k0base = blockIdx.y * kIters * 32;

  const bf16* Ab = R + (size_t)m0 * n + k0base;
  const bf16* Bb = R + (size_t)n0 * n + k0base;
  const int srow = t >> 2;
  const int schunk = (t & 3) * 8;

  floatx4 acc[4][4];
#pragma unroll
  for (int i = 0; i < 4; ++i)
#pragma unroll
    for (int j = 0; j < 4; ++j) acc[i][j] = (floatx4)0.0f;

  for (int kb = 0; kb < kIters; ++kb) {
    const int k0 = kb * 32;
    __syncthreads();
    GLD16(Ab + (size_t)srow * n + k0 + schunk,        As + (size_t)t * 8);
    GLD16(Ab + (size_t)(srow + 64) * n + k0 + schunk, As + (size_t)(t + 256) * 8);
    GLD16(Bb + (size_t)srow * n + k0 + schunk,        Bs + (size_t)t * 8);
    GLD16(Bb + (size_t)(srow + 64) * n + k0 + schunk, Bs + (size_t)(t + 256) * 8);
    __syncthreads();

    bf16x8 af[4], bfr[4];
#pragma unroll
    for (int mi = 0; mi < 4; ++mi)
      af[mi] = *(const bf16x8*)&As[(wr * 64 + mi * 16 + lr) * 32 + q * 8];
#pragma unroll
    for (int ni = 0; ni < 4; ++ni)
      bfr[ni] = *(const bf16x8*)&Bs[(wc * 64 + ni * 16 + lr) * 32 + q * 8];
#pragma unroll
    for (int mi = 0; mi < 4; ++mi)
#pragma unroll
      for (int ni = 0; ni < 4; ++ni)
        acc[mi][ni] = __builtin_amdgcn_mfma_f32_16x16x32_bf16(
            af[mi], bfr[ni], acc[mi][ni], 0, 0, 0);
  }

  const size_t so = ((size_t)blockIdx.y * gridDim.x + blockIdx.x) * 16384;
#pragma unroll
  for (int mi = 0; mi < 4; ++mi)
#pragma unroll
    for (int ni = 0; ni < 4; ++ni) {
      const int cl = wc * 64 + ni * 16 + lr;
      const int rb = wr * 64 + mi * 16 + q * 4;
#pragma unroll
      for (int r = 0; r < 4; ++r) {
        float v = acc[mi][ni][r];
        if (CsBf) CsBf[so + (size_t)(rb + r) * 128 + cl] = (bf16)v;
        else      CsF[so + (size_t)(rb + r) * 128 + cl] = v;
      }
    }
}

// Sum split-K slices (bf16 or fp32), write A (bf16 and/or fp32) with
// symmetric mirror, diag=0.
__global__ void sym_post(const bf16* __restrict__ CsBf, const float* __restrict__ CsF,
                         bf16* __restrict__ Abf, float* __restrict__ Af,
                         int k, int G, int pairs, int nz)
{
  int rem = blockIdx.x, bm = 0;
  while (rem >= G - bm) { rem -= G - bm; ++bm; }
  const int bn = bm + rem;
  const int i = threadIdx.x;
  const int r = bm * 128 + i;
  const size_t sbase = (size_t)blockIdx.x * 16384 + (size_t)i * 128;

  for (int jc = 0; jc < 128; jc += 16) {
    float v[16];
#pragma unroll
    for (int e = 0; e < 16; ++e) v[e] = 0.0f;
    for (int z = 0; z < nz; ++z) {
      const size_t off = sbase + (size_t)z * pairs * 16384 + jc;
      if (CsBf) {
        bf16x8 a = *(const bf16x8*)&CsBf[off];
        bf16x8 b = *(const bf16x8*)&CsBf[off + 8];
#pragma unroll
        for (int e = 0; e < 8; ++e) { v[e] += (float)a[e]; v[e + 8] += (float)b[e]; }
      } else {
#pragma unroll
        for (int e = 0; e < 16; e += 4) {
          floatx4 a = *(const floatx4*)&CsF[off + e];
#pragma unroll
          for (int j = 0; j < 4; ++j) v[e + j] += a[j];
        }
      }
    }
#pragma unroll
    for (int e = 0; e < 16; ++e) {
      const int c = bn * 128 + jc + e;
      const float val = (c == r) ? 0.0f : v[e];
      if (Abf) Abf[(size_t)r * k + c] = (bf16)val;
      if (Af)  Af[(size_t)r * k + c] = val;
      if (bm != bn) {
        if (Abf) Abf[(size_t)c * k + r] = (bf16)val;
        if (Af)  Af[(size_t)c * k + r] = val;
      }
    }
  }
}

// ---------------------------------------------------------------------------
// Aggregation (exact-int A in bf16, diag stored 0): Y += A @ Z (NP planes).
// NP compile-time: loops fully unroll (runtime NP spilled — round-10 lesson).
// ---------------------------------------------------------------------------
template <int NP>
__global__ __launch_bounds__(256) void agg_bf(
    const bf16* __restrict__ A, int lda,
    const bf16* __restrict__ Zh, const bf16* __restrict__ Zm, const bf16* __restrict__ Zl,
    int ldz, float* __restrict__ Y, int kIters)
{
  __shared__ __align__(16) bf16 As[128 * 32];
  __shared__ __align__(16) bf16 Zs[3][128 * 32];

  const int t = threadIdx.x;
  const int w = t >> 6, l = t & 63;
  const int wr = w >> 1, wc = w & 1;
  const int lr = l & 15, q = l >> 4;
  const int m0 = blockIdx.x * 128;
  const int k0base = blockIdx.y * kIters * 32;

  const int srow = t >> 2;
  const int schunk = (t & 3) * 8;

  floatx4 acc[4][4];
#pragma unroll
  for (int i = 0; i < 4; ++i)
#pragma unroll
    for (int j = 0; j < 4; ++j) acc[i][j] = (floatx4)0.0f;

  for (int kb = 0; kb < kIters; ++kb) {
    const int k0 = k0base + kb * 32;
    __syncthreads();
    GLD16(A + (size_t)(m0 + srow) * lda + k0 + schunk,        As + (size_t)t * 8);
    GLD16(A + (size_t)(m0 + srow + 64) * lda + k0 + schunk,   As + (size_t)(t + 256) * 8);
    GLD16(Zh + (size_t)srow * ldz + k0 + schunk,        Zs[0] + (size_t)t * 8);
    GLD16(Zh + (size_t)(srow + 64) * ldz + k0 + schunk, Zs[0] + (size_t)(t + 256) * 8);
    GLD16(Zm + (size_t)srow * ldz + k0 + schunk,        Zs[1] + (size_t)t * 8);
    GLD16(Zm + (size_t)(srow + 64) * ldz + k0 + schunk, Zs[1] + (size_t)(t + 256) * 8);
    if (NP > 2) {
      GLD16(Zl + (size_t)srow * ldz + k0 + schunk,        Zs[2] + (size_t)t * 8);
      GLD16(Zl + (size_t)(srow + 64) * ldz + k0 + schunk, Zs[2] + (size_t)(t + 256) * 8);
    }
    __syncthreads();

    bf16x8 af[4], bz[NP][4];
#pragma unroll
    for (int mi = 0; mi < 4; ++mi)
      af[mi] = *(const bf16x8*)&As[(wr * 64 + mi * 16 + lr) * 32 + q * 8];
#pragma unroll
    for (int s = 0; s < NP; ++s)
#pragma unroll
      for (int ni = 0; ni < 4; ++ni)
        bz[s][ni] = *(const bf16x8*)&Zs[s][(wc * 64 + ni * 16 + lr) * 32 + q * 8];
#pragma unroll
    for (int s = 0; s < NP; ++s)
#pragma unroll
      for (int mi = 0; mi < 4; ++mi)
#pragma unroll
        for (int ni = 0; ni < 4; ++ni)
          acc[mi][ni] = __builtin_amdgcn_mfma_f32_16x16x32_bf16(
              af[mi], bz[s][ni], acc[mi][ni], 0, 0, 0);
  }

#pragma unroll
  for (int mi = 0; mi < 4; ++mi)
#pragma unroll
    for (int ni = 0; ni < 4; ++ni) {
      const int col = wc * 64 + ni * 16 + lr;
      const int rowb = m0 + wr * 64 + mi * 16 + q * 4;
#pragma unroll
      for (int r = 0; r < 4; ++r)
        atomicAdd(&Y[(size_t)(rowb + r) * 128 + col], acc[mi][ni][r]);
    }
}

// ---------------------------------------------------------------------------
// Aggregation (fp32 A, on-the-fly 2-plane split, diag zeroed by index).
// ---------------------------------------------------------------------------
template <int NP>
__global__ __launch_bounds__(256) void agg_split(
    const float* __restrict__ A, int lda,
    const bf16* __restrict__ Zh, const bf16* __restrict__ Zm, const bf16* __restrict__ Zl,
    int ldz, float* __restrict__ Y, int kIters, int aTwo)
{
  __shared__ __align__(16) bf16 Ahs[128 * 32];
  __shared__ __align__(16) bf16 Als[128 * 32];
  __shared__ __align__(16) bf16 Zs[3][128 * 32];

  const int t = threadIdx.x;
  const int w = t >> 6, l = t & 63;
  const int wr = w >> 1, wc = w & 1;
  const int lr = l & 15, q = l >> 4;
  const int m0 = blockIdx.x * 128;
  const int k0base = blockIdx.y * kIters * 32;

  const int arow = t >> 1;
  const int acol = (t & 1) * 16;
  const int zrow = t >> 2;
  const int zchunk = (t & 3) * 8;

  floatx4 acc[4][4];
#pragma unroll
  for (int i = 0; i < 4; ++i)
#pragma unroll
    for (int j = 0; j < 4; ++j) acc[i][j] = (floatx4)0.0f;

  for (int kb = 0; kb < kIters; ++kb) {
    const int k0 = k0base + kb * 32;
    const float* asrc = A + (size_t)(m0 + arow) * lda + k0 + acol;
    floatx4 av[4];
#pragma unroll
    for (int i = 0; i < 4; ++i) av[i] = *(const floatx4*)(asrc + i * 4);

    __syncthreads();
    GLD16(Zh + (size_t)zrow * ldz + k0 + zchunk,        Zs[0] + (size_t)t * 8);
    GLD16(Zh + (size_t)(zrow + 64) * ldz + k0 + zchunk, Zs[0] + (size_t)(t + 256) * 8);
    GLD16(Zm + (size_t)zrow * ldz + k0 + zchunk,        Zs[1] + (size_t)t * 8);
    GLD16(Zm + (size_t)(zrow + 64) * ldz + k0 + zchunk, Zs[1] + (size_t)(t + 256) * 8);
    if (NP > 2) {
      GLD16(Zl + (size_t)zrow * ldz + k0 + zchunk,        Zs[2] + (size_t)t * 8);
      GLD16(Zl + (size_t)(zrow + 64) * ldz + k0 + zchunk, Zs[2] + (size_t)(t + 256) * 8);
    }

    bf16x8 ah[2], alo[2];
    const int grow = m0 + arow;
#pragma unroll
    for (int i = 0; i < 16; ++i) {
      float v = av[i >> 2][i & 3];
      if (k0 + acol + i == grow) v = 0.0f;
      bf16 h = (bf16)v;
      ah[i >> 3][i & 7] = h;
      alo[i >> 3][i & 7] = (bf16)(v - (float)h);
    }
    const int sbase = arow * 32 + acol;
    *(bf16x8*)&Ahs[sbase] = ah[0]; *(bf16x8*)&Ahs[sbase + 8] = ah[1];
    if (aTwo) { *(bf16x8*)&Als[sbase] = alo[0]; *(bf16x8*)&Als[sbase + 8] = alo[1]; }
    __syncthreads();

    bf16x8 afh[4], afl[4], bz[NP][4];
#pragma unroll
    for (int mi = 0; mi < 4; ++mi)
      afh[mi] = *(const bf16x8*)&Ahs[(wr * 64 + mi * 16 + lr) * 32 + q * 8];
#pragma unroll
    for (int s = 0; s < NP; ++s)
#pragma unroll
      for (int ni = 0; ni < 4; ++ni)
        bz[s][ni] = *(const bf16x8*)&Zs[s][(wc * 64 + ni * 16 + lr) * 32 + q * 8];
#pragma unroll
    for (int s = 0; s < NP; ++s)
#pragma unroll
      for (int mi = 0; mi < 4; ++mi)
#pragma unroll
        for (int ni = 0; ni < 4; ++ni)
          acc[mi][ni] = __builtin_amdgcn_mfma_f32_16x16x32_bf16(
              afh[mi], bz[s][ni], acc[mi][ni], 0, 0, 0);
    if (aTwo) {
#pragma unroll
      for (int mi = 0; mi < 4; ++mi)
        afl[mi] = *(const bf16x8*)&Als[(wr * 64 + mi * 16 + lr) * 32 + q * 8];
      constexpr int NL = (NP > 2) ? 2 : 1;
#pragma unroll
      for (int s = 0; s < NL; ++s)
#pragma unroll
        for (int mi = 0; mi < 4; ++mi)
#pragma unroll
          for (int ni = 0; ni < 4; ++ni)
            acc[mi][ni] = __builtin_amdgcn_mfma_f32_16x16x32_bf16(
                afl[mi], bz[s][ni], acc[mi][ni], 0, 0, 0);
    }
  }

#pragma unroll
  for (int mi = 0; mi < 4; ++mi)
#pragma unroll
    for (int ni = 0; ni < 4; ++ni) {
      const int col = wc * 64 + ni * 16 + lr;
      const int rowb = m0 + wr * 64 + mi * 16 + q * 4;
#pragma unroll
      for (int r = 0; r < 4; ++r)
        atomicAdd(&Y[(size_t)(rowb + r) * 128 + col], acc[mi][ni][r]);
    }
}

// ---------------------------------------------------------------------------
// Z[nr,128] = dn ⊙ (x @ W); x row = X[perm[row]]*vals[row]  (pool fusion)
//                       or  X[row] + up[inv[row]]            (unpool fusion)
// FULL=1: 6-term (2^-24), 3 planes. FULL=0: 3-term (2^-16), 2 planes.
// ---------------------------------------------------------------------------
template <int FULL>
__global__ __launch_bounds__(256) void xw_split(
    const float* __restrict__ X, const int* __restrict__ perm,
    const float* __restrict__ vals,
    const float* __restrict__ up, const int* __restrict__ inv,
    const bf16* __restrict__ Wh, const bf16* __restrict__ Wm, const bf16* __restrict__ Wl,
    const float* __restrict__ dnv, float* __restrict__ Z,
    bf16* __restrict__ Zht, bf16* __restrict__ Zmt, bf16* __restrict__ Zlt, int ldz,
    float* __restrict__ Agg, float* __restrict__ stats)
{
  __shared__ __align__(16) bf16 Xs[3][128 * 32];
  __shared__ __align__(16) bf16 Ws[3][128 * 32];

  const int t = threadIdx.x;
  if (blockIdx.x == 0) stats[t] = 0.0f;

  const int w = t >> 6, l = t & 63;
  const int wr = w >> 1, wc = w & 1;
  const int lr = l & 15, q = l >> 4;
  const int r0 = blockIdx.x * 128;

  const int srow = t >> 1;
  const int soff = (t & 1) * 16;
  const int sbase = srow * 32 + soff;

  const int row = r0 + srow;
  int grow = row;
  float scale = 1.0f;
  if (perm) { grow = perm[row]; scale = vals[row]; }
  const float* xrow = X + (size_t)grow * 128;
  const float* uprow = nullptr;
  if (up) { int j = inv[row]; if (j >= 0) uprow = up + (size_t)j * 128; }

  floatx4 acc[4][4];
#pragma unroll
  for (int i = 0; i < 4; ++i)
#pragma unroll
    for (int j = 0; j < 4; ++j) acc[i][j] = (floatx4)0.0f;

  const bf16* wsrc[3] = {Wh, Wm, Wl};

  for (int ks = 0; ks < 4; ++ks) {
    const int k0 = ks * 32;
    float xv[16];
#pragma unroll
    for (int i = 0; i < 16; i += 4) {
      floatx4 tmp = *(const floatx4*)(xrow + k0 + soff + i);
      if (uprow) {
        floatx4 u = *(const floatx4*)(uprow + k0 + soff + i);
        tmp += u;
      }
      xv[i] = tmp[0] * scale; xv[i + 1] = tmp[1] * scale;
      xv[i + 2] = tmp[2] * scale; xv[i + 3] = tmp[3] * scale;
    }
    bf16x8 wv[3][2];
#pragma unroll
    for (int s = 0; s < 3; ++s) {
      const bf16* ws = wsrc[s] + (size_t)srow * 128 + k0 + soff;
      wv[s][0] = *(const bf16x8*)ws;
      wv[s][1] = *(const bf16x8*)(ws + 8);
    }
    bf16x8 vh[2], vm[2], vl[2];
#pragma unroll
    for (int i = 0; i < 16; ++i) {
      float v = xv[i];
      bf16 h = (bf16)v; float r1 = v - (float)h;
      bf16 m = (bf16)r1; float r2 = r1 - (float)m;
      vh[i >> 3][i & 7] = h; vm[i >> 3][i & 7] = m; vl[i >> 3][i & 7] = (bf16)r2;
    }
    __syncthreads();
    *(bf16x8*)&Xs[0][sbase] = vh[0]; *(bf16x8*)&Xs[0][sbase + 8] = vh[1];
    *(bf16x8*)&Xs[1][sbase] = vm[0]; *(bf16x8*)&Xs[1][sbase + 8] = vm[1];
    *(bf16x8*)&Xs[2][sbase] = vl[0]; *(bf16x8*)&Xs[2][sbase + 8] = vl[1];
#pragma unroll
    for (int s = 0; s < 3; ++s) {
      *(bf16x8*)&Ws[s][sbase] = wv[s][0];
      *(bf16x8*)&Ws[s][sbase + 8] = wv[s][1];
    }
    __syncthreads();

    bf16x8 af[3][4], bfg[3][4];
#pragma unroll
    for (int s = 0; s < 3; ++s) {
#pragma unroll
      for (int mi = 0; mi < 4; ++mi)
        af[s][mi] = *(const bf16x8*)&Xs[s][(wr * 64 + mi * 16 + lr) * 32 + q * 8];
#pragma unroll
      for (int ni = 0; ni < 4; ++ni)
        bfg[s][ni] = *(const bf16x8*)&Ws[s][(wc * 64 + ni * 16 + lr) * 32 + q * 8];
    }
    constexpr int NT = FULL ? 6 : 3;
    constexpr int sa[6] = {0, 0, 1, 1, 0, 2};
    constexpr int sb[6] = {0, 1, 0, 1, 2, 0};
#pragma unroll
    for (int p = 0; p < NT; ++p)
#pragma unroll
      for (int mi = 0; mi < 4; ++mi)
#pragma unroll
        for (int ni = 0; ni < 4; ++ni)
          acc[mi][ni] = __builtin_amdgcn_mfma_f32_16x16x32_bf16(
              af[sa[p]][mi], bfg[sb[p]][ni], acc[mi][ni], 0, 0, 0);
  }

#pragma unroll
  for (int mi = 0; mi < 4; ++mi) {
    const int rowb = r0 + wr * 64 + mi * 16 + q * 4;
    float dnr[4];
#pragma unroll
    for (int r = 0; r < 4; ++r) dnr[r] = dnv[rowb + r];
#pragma unroll
    for (int ni = 0; ni < 4; ++ni) {
      const int col = wc * 64 + ni * 16 + lr;
      bf16x4 h4, m4, l4;
#pragma unroll
      for (int r = 0; r < 4; ++r) {
        float v = dnr[r] * acc[mi][ni][r];
        Z[(size_t)(rowb + r) * 128 + col] = v;
        Agg[(size_t)(rowb + r) * 128 + col] = 0.0f;
        bf16 h = (bf16)v; float r1 = v - (float)h;
        bf16 m = (bf16)r1; float r2 = r1 - (float)m;
        h4[r] = h; m4[r] = m; l4[r] = (bf16)r2;
      }
      *(bf16x4*)&Zht[(size_t)col * ldz + rowb] = h4;
      *(bf16x4*)&Zmt[(size_t)col * ldz + rowb] = m4;
      if (FULL) *(bf16x4*)&Zlt[(size_t)col * ldz + rowb] = l4;
    }
  }
}

// ---------------------------------------------------------------------------
// small kernels
// ---------------------------------------------------------------------------
__global__ void pnorm_kernel(const float* __restrict__ pw, float* __restrict__ invp) {
  __shared__ float red[128];
  int t = threadIdx.x;
  for (int l = 0; l < 3; ++l) {
    float v = pw[l * 128 + t];
    red[t] = v * v; __syncthreads();
    for (int off = 64; off; off >>= 1) {
      if (t < off) red[t] += red[t + off];
      __syncthreads();
    }
    if (t == 0) invp[l] = 1.0f / sqrtf(red[0]);
    __syncthreads();
  }
}

__global__ void split_w(const float* __restrict__ W, bf16* __restrict__ Wh,
                        bf16* __restrict__ Wm, bf16* __restrict__ Wl) {
  int idx = blockIdx.x * 256 + threadIdx.x;
  int l = idx >> 14, rem = idx & 16383, c = rem >> 7, k = rem & 127;
  float v = W[(l << 14) + (k << 7) + c];
  bf16 h = (bf16)v; float r1 = v - (float)h;
  bf16 m = (bf16)r1; float r2 = r1 - (float)m;
  Wh[idx] = h; Wm[idx] = m; Wl[idx] = (bf16)r2;
}

__global__ void adj2bf(const float* __restrict__ adj, bf16* __restrict__ ah,
                       float* __restrict__ dn, int n) {
  int r = blockIdx.x, t = threadIdx.x;
  const float* arow = adj + (size_t)r * n;
  bf16* orow = ah + (size_t)r * n;
  float sum = 0.f;
  for (int c4 = t * 4; c4 < n; c4 += 1024) {
    floatx4 v = *(const floatx4*)(arow + c4);
    bf16x4 o;
#pragma unroll
    for (int e = 0; e < 4; ++e) {
      float x = (c4 + e == r) ? 0.0f : v[e];
      sum += x; o[e] = (bf16)x;
    }
    *(bf16x4*)&orow[c4] = o;
  }
  __shared__ float red[256];
  red[t] = sum; __syncthreads();
  for (int off = 128; off; off >>= 1) {
    if (t < off) red[t] += red[t + off];
    __syncthreads();
  }
  if (t == 0) dn[r] = 1.0f / sqrtf(red[0] + 2.0f);
}

__global__ void dn_rows_bf(const bf16* __restrict__ A, int lda, float* __restrict__ dn,
                           int n) {
  int r = blockIdx.x, t = threadIdx.x;
  const bf16* row = A + (size_t)r * lda;
  float sum = 0.f;
  for (int c4 = t * 4; c4 < n; c4 += 1024) {
    bf16x4 v = *(const bf16x4*)&row[c4];
#pragma unroll
    for (int e = 0; e < 4; ++e) sum += (float)v[e];
  }
  __shared__ float red[256];
  red[t] = sum; __syncthreads();
  for (int off = 128; off; off >>= 1) {
    if (t < off) red[t] += red[t + off];
    __syncthreads();
  }
  if (t == 0) dn[r] = 1.0f / sqrtf(red[0] + 2.0f);
}

__global__ void dn_rows(const float* __restrict__ A, int lda, float* __restrict__ dn,
                        int n) {
  int r = blockIdx.x, t = threadIdx.x;
  const float* row = A + (size_t)r * lda;
  float sum = 0.f;
  for (int c = t; c < n; c += 256)
    if (c != r) sum += row[c];
  __shared__ float red[256];
  red[t] = sum; __syncthreads();
  for (int off = 128; off; off >>= 1) {
    if (t < off) red[t] += red[t + off];
    __syncthreads();
  }
  if (t == 0) dn[r] = 1.0f / sqrtf(red[0] + 2.0f);
}

// k-th largest via 4-round 8-bit radix select (snapshot-fixed select step).
__device__ inline unsigned f2u(float f) {
  unsigned u = __float_as_uint(f);
  return (u & 0x80000000u) ? ~u : (u | 0x80000000u);
}
__global__ __launch_bounds__(1024) void kth_radix(
    const float* __restrict__ s, int n, int k, float* __restrict__ out)
{
  __shared__ int hist[256];
  __shared__ int suf[256];
  __shared__ unsigned sh_prefix;
  __shared__ int sh_krem;
  const int t = threadIdx.x;
  if (t == 0) { sh_prefix = 0; sh_krem = k; }

  for (int round = 0; round < 4; ++round) {
    const int shift = 24 - 8 * round;
    if (t < 256) hist[t] = 0;
    __syncthreads();
    const unsigned pref = sh_prefix;   // snapshot after barrier
    const int krem = sh_krem;          // snapshot after barrier
    for (int i = t; i < n; i += 1024) {
      unsigned u = f2u(s[i]);
      if (round == 0 || (u >> (shift + 8)) == pref)
        atomicAdd(&hist[(u >> shift) & 255], 1);
    }
    __syncthreads();
    if (t < 256) suf[t] = hist[255 - t];
    __syncthreads();
    for (int off = 1; off < 256; off <<= 1) {
      int v = (t < 256 && t >= off) ? suf[t - off] : 0;
      __syncthreads();
      if (t < 256) suf[t] += v;
      __syncthreads();
    }
    if (t < 256) {
      int prev = (t == 0) ? 0 : suf[t - 1];
      if (suf[t] >= krem && prev < krem) {
        sh_prefix = (pref << 8) | (unsigned)(255 - t);
        sh_krem = krem - prev;
      }
    }
    __syncthreads();
  }
  if (t == 0) {
    unsigned u = sh_prefix;
    out[0] = (u & 0x80000000u) ? __uint_as_float(u & 0x7fffffffu)
                               : __uint_as_float(~u);
  }
}

// deterministic compaction (+ inverse perm): s>thr asc idx, ties asc idx.
__global__ void compact_kernel(const float* __restrict__ s, const float* __restrict__ thrp,
                               int n, int k, int* __restrict__ perm,
                               float* __restrict__ vals, int* __restrict__ inv) {
  __shared__ int cg[1024], ce[1024];
  int tid = threadIdx.x;
  float thr = *thrp;
  for (int i = tid; i < n; i += 1024) inv[i] = -1;
  int chunk = n >> 10;
  int beg = tid * chunk;
  int g = 0, e = 0;
  for (int i = 0; i < chunk; ++i) {
    float v = s[beg + i];
    g += (v > thr); e += (v == thr);
  }
  cg[tid] = g; ce[tid] = e; __syncthreads();
  for (int off = 1; off < 1024; off <<= 1) {
    int a = (tid >= off) ? cg[tid - off] : 0;
    int b = (tid >= off) ? ce[tid - off] : 0;
    __syncthreads();
    cg[tid] += a; ce[tid] += b;
    __syncthreads();
  }
  int total_gt = cg[1023];
  int pg = cg[tid] - g;
  int pe = ce[tid] - e;
  int need = k - total_gt;
  for (int i = 0; i < chunk; ++i) {
    float v = s[beg + i];
    if (v > thr) {
      if (pg < k) { perm[pg] = beg + i; vals[pg] = v; inv[beg + i] = pg; }
      ++pg;
    } else if (v == thr) {
      if (pe < need && total_gt + pe < k) {
        perm[total_gt + pe] = beg + i; vals[total_gt + pe] = v;
        inv[beg + i] = total_gt + pe;
      }
      ++pe;
    }
  }
}

__global__ void gather_bf(const bf16* __restrict__ src, int lda,
                          const int* __restrict__ perm, bf16* __restrict__ R, int n) {
  int j = blockIdx.x, t = threadIdx.x;
  int r = perm[j];
  const bf16* s = src + (size_t)r * lda;
  bf16* o = R + (size_t)j * n;
  for (int c4 = t * 4; c4 < n; c4 += 1024) {
    bf16x4 v = *(const bf16x4*)&s[c4];
    if (r >= c4 && r < c4 + 4) v[r - c4] = (bf16)1.0f;
    *(bf16x4*)&o[c4] = v;
  }
}

__global__ void gather_f32(const float* __restrict__ src, int lda,
                           const int* __restrict__ perm, bf16* __restrict__ R, int n) {
  int j = blockIdx.x, t = threadIdx.x;
  int r = perm[j];
  const float* s = src + (size_t)r * lda;
  bf16* o = R + (size_t)j * n;
  for (int c4 = t * 4; c4 < n; c4 += 1024) {
    floatx4 v = *(const floatx4*)(s + c4);
    bf16x4 ob;
#pragma unroll
    for (int e = 0; e < 4; ++e)
      ob[e] = (c4 + e == r) ? (bf16)1.0f : (bf16)v[e];
    *(bf16x4*)&o[c4] = ob;
  }
}

// y = dn[r]*(Agg + 2*Z) + bias; relu?; write Agg in-place; BN col stats.
__global__ void gcn_post(float* __restrict__ acc, const float* __restrict__ Zf,
                         const float* __restrict__ dn, const float* __restrict__ bias,
                         float* __restrict__ stats, int relu) {
  int c = threadIdx.x;
  int r0 = blockIdx.x * 16;
  float b = bias[c];
  float s = 0.f, qq = 0.f;
  for (int i = 0; i < 16; ++i) {
    int r = r0 + i;
    float v = dn[r] * (acc[(size_t)r * 128 + c] + 2.0f * Zf[(size_t)r * 128 + c]) + b;
    if (relu) v = fmaxf(v, 0.f);
    acc[(size_t)r * 128 + c] = v;
    s += v; qq += v * v;
  }
  atomicAdd(&stats[c], s);
  atomicAdd(&stats[128 + c], qq);
}

// BN apply (coef recomputed per block) + optional fused pooling score.
__global__ void bn_apply(const float* __restrict__ H, const float* __restrict__ stats,
                         const float* __restrict__ g, const float* __restrict__ b,
                         int n, float* __restrict__ xout,
                         const float* __restrict__ pw, const float* __restrict__ invp,
                         float* __restrict__ scores) {
  int r = blockIdx.x, c = threadIdx.x;
  float m = stats[c] / n;
  float var = stats[128 + c] / n - m * m;
  float sc = g[c] / sqrtf(var + 1e-5f);
  float off = b[c] - m * sc;
  float v = sc * H[(size_t)r * 128 + c] + off;
  xout[(size_t)r * 128 + c] = v;
  if (pw) {
    __shared__ float red[128];
    red[c] = v * pw[c]; __syncthreads();
    for (int o = 64; o; o >>= 1) {
      if (c < o) red[c] += red[c + o];
      __syncthreads();
    }
    if (c == 0) scores[r] = tanhf(red[0] * invp[0]);
  }
}

// ---------------------------------------------------------------------------
extern "C" void kernel_launch(void* const* d_in, const int* in_sizes, int n_in,
                              void* d_out, int out_size, void* d_ws, size_t ws_size,
                              hipStream_t stream) {
  const float* x_in   = (const float*)d_in[0];
  const float* adj    = (const float*)d_in[1];
  const float* conv_w = (const float*)d_in[2];
  const float* conv_b = (const float*)d_in[3];
  const float* pool_w = (const float*)d_in[4];
  const float* bn_g   = (const float*)d_in[5];
  const float* bn_b   = (const float*)d_in[6];
  float* out = (float*)d_out;
  (void)in_sizes; (void)n_in; (void)out_size; (void)ws_size;

  char* p = (char*)d_ws;
  auto alloc = [&](size_t bytes) -> void* {
    void* r = (void*)p;
    p += (bytes + 255) & ~(size_t)255;
    return r;
  };
  bf16*  Ah0bf = (bf16*)alloc(4096ull * 4096 * 2);
  bf16*  A1bf  = (bf16*)alloc(2048ull * 2048 * 2);
  float* A2f   = (float*)alloc(1024ull * 1024 * 4);
  float* A3f   = (float*)alloc(512ull * 512 * 4);
  bf16*  Rbuf  = (bf16*)alloc(2048ull * 4096 * 2);
  void*  Cs    = alloc(136ull * 8 * 16384 * 2);   // 35.7MB: L1 bf16x8 / L2,3 fp32x4,8
  float* Z     = (float*)alloc(4096ull * 128 * 4);
  bf16*  Zht   = (bf16*)alloc(128ull * 4096 * 2);
  bf16*  Zmt   = (bf16*)alloc(128ull * 4096 * 2);
  bf16*  Zlt   = (bf16*)alloc(128ull * 4096 * 2);
  float* Agg   = (float*)alloc(4096ull * 128 * 4);
  float* res0  = (float*)alloc(4096ull * 128 * 4);
  float* res1  = (float*)alloc(2048ull * 128 * 4);
  float* res2  = (float*)alloc(1024ull * 128 * 4);
  float* xb0   = (float*)alloc(512ull * 128 * 4);
  float* xb1   = (float*)alloc(1024ull * 128 * 4);
  float* xb2   = (float*)alloc(2048ull * 128 * 4);
  bf16*  Wh    = (bf16*)alloc(7ull * 16384 * 2);
  bf16*  Wm    = (bf16*)alloc(7ull * 16384 * 2);
  bf16*  Wl    = (bf16*)alloc(7ull * 16384 * 2);
  float* scores = (float*)alloc(4096 * 4);
  float* thrb  = (float*)alloc(256);
  int*   perm0 = (int*)alloc(2048 * 4);
  int*   perm1 = (int*)alloc(1024 * 4);
  int*   perm2 = (int*)alloc(512 * 4);
  int*   inv0  = (int*)alloc(4096 * 4);
  int*   inv1  = (int*)alloc(2048 * 4);
  int*   inv2  = (int*)alloc(1024 * 4);
  float* vals0 = (float*)alloc(2048 * 4);
  float* vals1 = (float*)alloc(1024 * 4);
  float* vals2 = (float*)alloc(512 * 4);
  float* dn0   = (float*)alloc(4096 * 4);
  float* dn1   = (float*)alloc(2048 * 4);
  float* dn2   = (float*)alloc(1024 * 4);
  float* dn3   = (float*)alloc(512 * 4);
  float* invp  = (float*)alloc(256);
  float* stats = (float*)alloc(1024);

  // GCN layer; (perm,vals) fuses pooling gather, (up,inv) fuses unpool add;
  // (pw,ip) fuses the next pool's score into bn_apply.
  auto gcn = [&](int nr, const bf16* Abf, const float* Af32, const float* dnv,
                 int layer, const float* xsrc, const int* perm, const float* vals,
                 const float* up, const int* inv, float* xout, int relu, int aTwo,
                 const float* pw, const float* ip, int full) {
    if (full)
      xw_split<1><<<nr / 128, 256, 0, stream>>>(
          xsrc, perm, vals, up, inv,
          Wh + layer * 16384, Wm + layer * 16384, Wl + layer * 16384, dnv,
          Z, Zht, Zmt, Zlt, nr, Agg, stats);
    else
      xw_split<0><<<nr / 128, 256, 0, stream>>>(
          xsrc, perm, vals, up, inv,
          Wh + layer * 16384, Wm + layer * 16384, Wl + layer * 16384, dnv,
          Z, Zht, Zmt, Zlt, nr, Agg, stats);
    if (Abf) {
      if (full)
        agg_bf<3><<<dim3(nr / 128, 8), 256, 0, stream>>>(
            Abf, nr, Zht, Zmt, Zlt, nr, Agg, nr / 256);
      else
        agg_bf<2><<<dim3(nr / 128, 8), 256, 0, stream>>>(
            Abf, nr, Zht, Zmt, Zlt, nr, Agg, nr / 256);
    } else {
      if (full)
        agg_split<3><<<dim3(nr / 128, 8), 256, 0, stream>>>(
            Af32, nr, Zht, Zmt, Zlt, nr, Agg, nr / 256, aTwo);
      else
        agg_split<2><<<dim3(nr / 128, 8), 256, 0, stream>>>(
            Af32, nr, Zht, Zmt, Zlt, nr, Agg, nr / 256, aTwo);
    }
    gcn_post<<<nr / 16, 128, 0, stream>>>(Agg, Z, dnv, conv_b + layer * 128, stats, relu);
    bn_apply<<<nr, 128, 0, stream>>>(Agg, stats, bn_g + layer * 128, bn_b + layer * 128,
                                     nr, xout, pw, ip, scores);
  };

  // Pool: top-k -> gather R=(A+I)[perm] -> upper-tri R R^T (slices, no
  // atomics) -> sym_post -> dn. sliceBf=1: bf16 slices (exact-int partials,
  // L1 only) lets splitZ=8 at the same slice traffic as fp32 splitZ=4.
  auto pool = [&](int n, const bf16* srcBf, const float* srcF32,
                  bf16* outBf, float* outF32, float* dnNew,
                  int* perm, float* vals, int* inv, int splitZ, int sliceBf) {
    int k = n / 2, G = k / 128, pairs = G * (G + 1) / 2;
    kth_radix<<<1, 1024, 0, stream>>>(scores, n, k, thrb);
    compact_kernel<<<1, 1024, 0, stream>>>(scores, thrb, n, k, perm, vals, inv);
    if (srcBf) gather_bf<<<k, 256, 0, stream>>>(srcBf, n, perm, Rbuf, n);
    else       gather_f32<<<k, 256, 0, stream>>>(srcF32, n, perm, Rbuf, n);
    gemm_sym<<<dim3(pairs, splitZ), 256, 0, stream>>>(
        Rbuf, sliceBf ? (bf16*)Cs : nullptr, sliceBf ? nullptr : (float*)Cs,
        n, n / (splitZ * 32), G);
    sym_post<<<pairs, 128, 0, stream>>>(
        sliceBf ? (const bf16*)Cs : nullptr, sliceBf ? nullptr : (const float*)Cs,
        outBf, outF32, k, G, pairs, splitZ);
    if (outBf) dn_rows_bf<<<k, 256, 0, stream>>>(outBf, k, dnNew, k);
    else       dn_rows<<<k, 256, 0, stream>>>(outF32, k, dnNew, k);
  };

  // ---- prep ----
  pnorm_kernel<<<1, 128, 0, stream>>>(pool_w, invp);
  split_w<<<448, 256, 0, stream>>>(conv_w, Wh, Wm, Wl);
  adj2bf<<<4096, 256, 0, stream>>>(adj, Ah0bf, dn0, 4096);

  // ---- down ---- (layers 0-2 feed top-k selections: full precision)
  gcn(4096, Ah0bf, nullptr, dn0, 0, x_in, nullptr, nullptr, nullptr, nullptr,
      res0, 1, 0, pool_w + 0, invp + 0, 1);
  pool(4096, Ah0bf, nullptr, A1bf, nullptr, dn1, perm0, vals0, inv0, 8, 1);
  gcn(2048, A1bf, nullptr, dn1, 1, res0, perm0, vals0, nullptr, nullptr,
      res1, 1, 0, pool_w + 128, invp + 1, 1);
  pool(2048, A1bf, nullptr, nullptr, A2f, dn2, perm1, vals1, inv1, 4, 0);
  gcn(1024, nullptr, A2f, dn2, 2, res1, perm1, vals1, nullptr, nullptr,
      res2, 1, 1, pool_w + 256, invp + 2, 1);
  pool(1024, nullptr, A2f, nullptr, A3f, dn3, perm2, vals2, inv2, 8, 0);
  // ---- layers 3-6 are value-path only: trimmed precision ----
  gcn(512, nullptr, A3f, dn3, 3, res2, perm2, vals2, nullptr, nullptr,
      xb0, 1, 1, nullptr, nullptr, 0);

  // ---- up ---- (unpool add fused into xw_split; res buffers stay intact)
  gcn(1024, nullptr, A2f, dn2, 4, res2, nullptr, nullptr, xb0, inv2,
      xb1, 1, 1, nullptr, nullptr, 0);
  gcn(2048, A1bf, nullptr, dn1, 5, res1, nullptr, nullptr, xb1, inv1,
      xb2, 1, 0, nullptr, nullptr, 0);
  gcn(4096, Ah0bf, nullptr, dn0, 6, res0, nullptr, nullptr, xb2, inv0,
      out, 0, 0, nullptr, nullptr, 0);
}

// Round 13
// 642.032 us; speedup vs baseline: 1.0194x; 1.0194x over previous
//
#include <hip/hip_runtime.h>
#include <cstdint>
#include <cstddef>

typedef __bf16 bf16;
typedef __bf16 bf16x8 __attribute__((ext_vector_type(8)));
typedef __bf16 bf16x4 __attribute__((ext_vector_type(4)));
typedef float floatx4 __attribute__((ext_vector_type(4)));

#define GLD16(gp, lp) __builtin_amdgcn_global_load_lds( \
    (const __attribute__((address_space(1))) void*)(gp), \
    (__attribute__((address_space(3))) void*)(lp), 16, 0, 0)

// ---------------------------------------------------------------------------
// Symmetric augment GEMM: upper-tri 128x128 block pairs of C = R * R^T,
// R [k x n] bf16. Per-(pair,z) slices, no atomics (bf16 or fp32 slices).
// ---------------------------------------------------------------------------
__global__ __launch_bounds__(256) void gemm_sym(
    const bf16* __restrict__ R, bf16* __restrict__ CsBf, float* __restrict__ CsF,
    int n /*lda = K*/, int kIters, int G)
{
  __shared__ __align__(16) bf16 smem[2 * 128 * 32];
  bf16* As = smem;
  bf16* Bs = smem + 128 * 32;

  int rem = blockIdx.x, bm = 0;
  while (rem >= G - bm) { rem -= G - bm; ++bm; }
  const int bn = bm + rem;
  const int m0 = bm * 128, n0 = bn * 128;

  const int t = threadIdx.x;
  const int w = t >> 6, l = t & 63;
  const int wr = w >> 1, wc = w & 1;
  const int lr = l & 15, q = l >> 4;
  const int k0base = blockIdx.y * kIters * 32;

  const bf16* Ab = R + (size_t)m0 * n + k0base;
  const bf16* Bb = R + (size_t)n0 * n + k0base;
  const int srow = t >> 2;
  const int schunk = (t & 3) * 8;

  floatx4 acc[4][4];
#pragma unroll
  for (int i = 0; i < 4; ++i)
#pragma unroll
    for (int j = 0; j < 4; ++j) acc[i][j] = (floatx4)0.0f;

  for (int kb = 0; kb < kIters; ++kb) {
    const int k0 = kb * 32;
    __syncthreads();
    GLD16(Ab + (size_t)srow * n + k0 + schunk,        As + (size_t)t * 8);
    GLD16(Ab + (size_t)(srow + 64) * n + k0 + schunk, As + (size_t)(t + 256) * 8);
    GLD16(Bb + (size_t)srow * n + k0 + schunk,        Bs + (size_t)t * 8);
    GLD16(Bb + (size_t)(srow + 64) * n + k0 + schunk, Bs + (size_t)(t + 256) * 8);
    __syncthreads();

    bf16x8 af[4], bfr[4];
#pragma unroll
    for (int mi = 0; mi < 4; ++mi)
      af[mi] = *(const bf16x8*)&As[(wr * 64 + mi * 16 + lr) * 32 + q * 8];
#pragma unroll
    for (int ni = 0; ni < 4; ++ni)
      bfr[ni] = *(const bf16x8*)&Bs[(wc * 64 + ni * 16 + lr) * 32 + q * 8];
#pragma unroll
    for (int mi = 0; mi < 4; ++mi)
#pragma unroll
      for (int ni = 0; ni < 4; ++ni)
        acc[mi][ni] = __builtin_amdgcn_mfma_f32_16x16x32_bf16(
            af[mi], bfr[ni], acc[mi][ni], 0, 0, 0);
  }

  const size_t so = ((size_t)blockIdx.y * gridDim.x + blockIdx.x) * 16384;
#pragma unroll
  for (int mi = 0; mi < 4; ++mi)
#pragma unroll
    for (int ni = 0; ni < 4; ++ni) {
      const int cl = wc * 64 + ni * 16 + lr;
      const int rb = wr * 64 + mi * 16 + q * 4;
#pragma unroll
      for (int r = 0; r < 4; ++r) {
        float v = acc[mi][ni][r];
        if (CsBf) CsBf[so + (size_t)(rb + r) * 128 + cl] = (bf16)v;
        else      CsF[so + (size_t)(rb + r) * 128 + cl] = v;
      }
    }
}

// Sum split-K slices (bf16 or fp32), write A (bf16 and/or fp32) with
// symmetric mirror, diag=0.
__global__ void sym_post(const bf16* __restrict__ CsBf, const float* __restrict__ CsF,
                         bf16* __restrict__ Abf, float* __restrict__ Af,
                         int k, int G, int pairs, int nz)
{
  int rem = blockIdx.x, bm = 0;
  while (rem >= G - bm) { rem -= G - bm; ++bm; }
  const int bn = bm + rem;
  const int i = threadIdx.x;
  const int r = bm * 128 + i;
  const size_t sbase = (size_t)blockIdx.x * 16384 + (size_t)i * 128;

  for (int jc = 0; jc < 128; jc += 16) {
    float v[16];
#pragma unroll
    for (int e = 0; e < 16; ++e) v[e] = 0.0f;
    for (int z = 0; z < nz; ++z) {
      const size_t off = sbase + (size_t)z * pairs * 16384 + jc;
      if (CsBf) {
        bf16x8 a = *(const bf16x8*)&CsBf[off];
        bf16x8 b = *(const bf16x8*)&CsBf[off + 8];
#pragma unroll
        for (int e = 0; e < 8; ++e) { v[e] += (float)a[e]; v[e + 8] += (float)b[e]; }
      } else {
#pragma unroll
        for (int e = 0; e < 16; e += 4) {
          floatx4 a = *(const floatx4*)&CsF[off + e];
#pragma unroll
          for (int j = 0; j < 4; ++j) v[e + j] += a[j];
        }
      }
    }
#pragma unroll
    for (int e = 0; e < 16; ++e) {
      const int c = bn * 128 + jc + e;
      const float val = (c == r) ? 0.0f : v[e];
      if (Abf) Abf[(size_t)r * k + c] = (bf16)val;
      if (Af)  Af[(size_t)r * k + c] = val;
      if (bm != bn) {
        if (Abf) Abf[(size_t)c * k + r] = (bf16)val;
        if (Af)  Af[(size_t)c * k + r] = val;
      }
    }
  }
}

// ---------------------------------------------------------------------------
// Aggregation (exact-int A in bf16, diag stored 0): Y += A @ Z (NP planes).
// ---------------------------------------------------------------------------
template <int NP>
__global__ __launch_bounds__(256) void agg_bf(
    const bf16* __restrict__ A, int lda,
    const bf16* __restrict__ Zh, const bf16* __restrict__ Zm, const bf16* __restrict__ Zl,
    int ldz, float* __restrict__ Y, int kIters)
{
  __shared__ __align__(16) bf16 As[128 * 32];
  __shared__ __align__(16) bf16 Zs[3][128 * 32];

  const int t = threadIdx.x;
  const int w = t >> 6, l = t & 63;
  const int wr = w >> 1, wc = w & 1;
  const int lr = l & 15, q = l >> 4;
  const int m0 = blockIdx.x * 128;
  const int k0base = blockIdx.y * kIters * 32;

  const int srow = t >> 2;
  const int schunk = (t & 3) * 8;

  floatx4 acc[4][4];
#pragma unroll
  for (int i = 0; i < 4; ++i)
#pragma unroll
    for (int j = 0; j < 4; ++j) acc[i][j] = (floatx4)0.0f;

  for (int kb = 0; kb < kIters; ++kb) {
    const int k0 = k0base + kb * 32;
    __syncthreads();
    GLD16(A + (size_t)(m0 + srow) * lda + k0 + schunk,        As + (size_t)t * 8);
    GLD16(A + (size_t)(m0 + srow + 64) * lda + k0 + schunk,   As + (size_t)(t + 256) * 8);
    GLD16(Zh + (size_t)srow * ldz + k0 + schunk,        Zs[0] + (size_t)t * 8);
    GLD16(Zh + (size_t)(srow + 64) * ldz + k0 + schunk, Zs[0] + (size_t)(t + 256) * 8);
    GLD16(Zm + (size_t)srow * ldz + k0 + schunk,        Zs[1] + (size_t)t * 8);
    GLD16(Zm + (size_t)(srow + 64) * ldz + k0 + schunk, Zs[1] + (size_t)(t + 256) * 8);
    if (NP > 2) {
      GLD16(Zl + (size_t)srow * ldz + k0 + schunk,        Zs[2] + (size_t)t * 8);
      GLD16(Zl + (size_t)(srow + 64) * ldz + k0 + schunk, Zs[2] + (size_t)(t + 256) * 8);
    }
    __syncthreads();

    bf16x8 af[4], bz[NP][4];
#pragma unroll
    for (int mi = 0; mi < 4; ++mi)
      af[mi] = *(const bf16x8*)&As[(wr * 64 + mi * 16 + lr) * 32 + q * 8];
#pragma unroll
    for (int s = 0; s < NP; ++s)
#pragma unroll
      for (int ni = 0; ni < 4; ++ni)
        bz[s][ni] = *(const bf16x8*)&Zs[s][(wc * 64 + ni * 16 + lr) * 32 + q * 8];
#pragma unroll
    for (int s = 0; s < NP; ++s)
#pragma unroll
      for (int mi = 0; mi < 4; ++mi)
#pragma unroll
        for (int ni = 0; ni < 4; ++ni)
          acc[mi][ni] = __builtin_amdgcn_mfma_f32_16x16x32_bf16(
              af[mi], bz[s][ni], acc[mi][ni], 0, 0, 0);
  }

#pragma unroll
  for (int mi = 0; mi < 4; ++mi)
#pragma unroll
    for (int ni = 0; ni < 4; ++ni) {
      const int col = wc * 64 + ni * 16 + lr;
      const int rowb = m0 + wr * 64 + mi * 16 + q * 4;
#pragma unroll
      for (int r = 0; r < 4; ++r)
        atomicAdd(&Y[(size_t)(rowb + r) * 128 + col], acc[mi][ni][r]);
    }
}

// ---------------------------------------------------------------------------
// Aggregation (fp32 A, on-the-fly 2-plane split, diag zeroed by index).
// ---------------------------------------------------------------------------
template <int NP>
__global__ __launch_bounds__(256) void agg_split(
    const float* __restrict__ A, int lda,
    const bf16* __restrict__ Zh, const bf16* __restrict__ Zm, const bf16* __restrict__ Zl,
    int ldz, float* __restrict__ Y, int kIters, int aTwo)
{
  __shared__ __align__(16) bf16 Ahs[128 * 32];
  __shared__ __align__(16) bf16 Als[128 * 32];
  __shared__ __align__(16) bf16 Zs[3][128 * 32];

  const int t = threadIdx.x;
  const int w = t >> 6, l = t & 63;
  const int wr = w >> 1, wc = w & 1;
  const int lr = l & 15, q = l >> 4;
  const int m0 = blockIdx.x * 128;
  const int k0base = blockIdx.y * kIters * 32;

  const int arow = t >> 1;
  const int acol = (t & 1) * 16;
  const int zrow = t >> 2;
  const int zchunk = (t & 3) * 8;

  floatx4 acc[4][4];
#pragma unroll
  for (int i = 0; i < 4; ++i)
#pragma unroll
    for (int j = 0; j < 4; ++j) acc[i][j] = (floatx4)0.0f;

  for (int kb = 0; kb < kIters; ++kb) {
    const int k0 = k0base + kb * 32;
    const float* asrc = A + (size_t)(m0 + arow) * lda + k0 + acol;
    floatx4 av[4];
#pragma unroll
    for (int i = 0; i < 4; ++i) av[i] = *(const floatx4*)(asrc + i * 4);

    __syncthreads();
    GLD16(Zh + (size_t)zrow * ldz + k0 + zchunk,        Zs[0] + (size_t)t * 8);
    GLD16(Zh + (size_t)(zrow + 64) * ldz + k0 + zchunk, Zs[0] + (size_t)(t + 256) * 8);
    GLD16(Zm + (size_t)zrow * ldz + k0 + zchunk,        Zs[1] + (size_t)t * 8);
    GLD16(Zm + (size_t)(zrow + 64) * ldz + k0 + zchunk, Zs[1] + (size_t)(t + 256) * 8);
    if (NP > 2) {
      GLD16(Zl + (size_t)zrow * ldz + k0 + zchunk,        Zs[2] + (size_t)t * 8);
      GLD16(Zl + (size_t)(zrow + 64) * ldz + k0 + zchunk, Zs[2] + (size_t)(t + 256) * 8);
    }

    bf16x8 ah[2], alo[2];
    const int grow = m0 + arow;
#pragma unroll
    for (int i = 0; i < 16; ++i) {
      float v = av[i >> 2][i & 3];
      if (k0 + acol + i == grow) v = 0.0f;
      bf16 h = (bf16)v;
      ah[i >> 3][i & 7] = h;
      alo[i >> 3][i & 7] = (bf16)(v - (float)h);
    }
    const int sbase = arow * 32 + acol;
    *(bf16x8*)&Ahs[sbase] = ah[0]; *(bf16x8*)&Ahs[sbase + 8] = ah[1];
    if (aTwo) { *(bf16x8*)&Als[sbase] = alo[0]; *(bf16x8*)&Als[sbase + 8] = alo[1]; }
    __syncthreads();

    bf16x8 afh[4], afl[4], bz[NP][4];
#pragma unroll
    for (int mi = 0; mi < 4; ++mi)
      afh[mi] = *(const bf16x8*)&Ahs[(wr * 64 + mi * 16 + lr) * 32 + q * 8];
#pragma unroll
    for (int s = 0; s < NP; ++s)
#pragma unroll
      for (int ni = 0; ni < 4; ++ni)
        bz[s][ni] = *(const bf16x8*)&Zs[s][(wc * 64 + ni * 16 + lr) * 32 + q * 8];
#pragma unroll
    for (int s = 0; s < NP; ++s)
#pragma unroll
      for (int mi = 0; mi < 4; ++mi)
#pragma unroll
        for (int ni = 0; ni < 4; ++ni)
          acc[mi][ni] = __builtin_amdgcn_mfma_f32_16x16x32_bf16(
              afh[mi], bz[s][ni], acc[mi][ni], 0, 0, 0);
    if (aTwo) {
#pragma unroll
      for (int mi = 0; mi < 4; ++mi)
        afl[mi] = *(const bf16x8*)&Als[(wr * 64 + mi * 16 + lr) * 32 + q * 8];
      constexpr int NL = (NP > 2) ? 2 : 1;
#pragma unroll
      for (int s = 0; s < NL; ++s)
#pragma unroll
        for (int mi = 0; mi < 4; ++mi)
#pragma unroll
          for (int ni = 0; ni < 4; ++ni)
            acc[mi][ni] = __builtin_amdgcn_mfma_f32_16x16x32_bf16(
                afl[mi], bz[s][ni], acc[mi][ni], 0, 0, 0);
    }
  }

#pragma unroll
  for (int mi = 0; mi < 4; ++mi)
#pragma unroll
    for (int ni = 0; ni < 4; ++ni) {
      const int col = wc * 64 + ni * 16 + lr;
      const int rowb = m0 + wr * 64 + mi * 16 + q * 4;
#pragma unroll
      for (int r = 0; r < 4; ++r)
        atomicAdd(&Y[(size_t)(rowb + r) * 128 + col], acc[mi][ni][r]);
    }
}

// ---------------------------------------------------------------------------
// Z[nr,128] = dn ⊙ (x @ W); x row = X[perm[row]]*vals[row]  (pool fusion)
//                       or  X[row] + up[inv[row]]            (unpool fusion)
// FULL=1: 6-term (2^-24), 3 planes. FULL=0: 3-term (2^-16), 2 planes.
// ---------------------------------------------------------------------------
template <int FULL>
__global__ __launch_bounds__(256) void xw_split(
    const float* __restrict__ X, const int* __restrict__ perm,
    const float* __restrict__ vals,
    const float* __restrict__ up, const int* __restrict__ inv,
    const bf16* __restrict__ Wh, const bf16* __restrict__ Wm, const bf16* __restrict__ Wl,
    const float* __restrict__ dnv, float* __restrict__ Z,
    bf16* __restrict__ Zht, bf16* __restrict__ Zmt, bf16* __restrict__ Zlt, int ldz,
    float* __restrict__ Agg, float* __restrict__ stats)
{
  __shared__ __align__(16) bf16 Xs[3][128 * 32];
  __shared__ __align__(16) bf16 Ws[3][128 * 32];

  const int t = threadIdx.x;
  if (blockIdx.x == 0) stats[t] = 0.0f;

  const int w = t >> 6, l = t & 63;
  const int wr = w >> 1, wc = w & 1;
  const int lr = l & 15, q = l >> 4;
  const int r0 = blockIdx.x * 128;

  const int srow = t >> 1;
  const int soff = (t & 1) * 16;
  const int sbase = srow * 32 + soff;

  const int row = r0 + srow;
  int grow = row;
  float scale = 1.0f;
  if (perm) { grow = perm[row]; scale = vals[row]; }
  const float* xrow = X + (size_t)grow * 128;
  const float* uprow = nullptr;
  if (up) { int j = inv[row]; if (j >= 0) uprow = up + (size_t)j * 128; }

  floatx4 acc[4][4];
#pragma unroll
  for (int i = 0; i < 4; ++i)
#pragma unroll
    for (int j = 0; j < 4; ++j) acc[i][j] = (floatx4)0.0f;

  const bf16* wsrc[3] = {Wh, Wm, Wl};

  for (int ks = 0; ks < 4; ++ks) {
    const int k0 = ks * 32;
    float xv[16];
#pragma unroll
    for (int i = 0; i < 16; i += 4) {
      floatx4 tmp = *(const floatx4*)(xrow + k0 + soff + i);
      if (uprow) {
        floatx4 u = *(const floatx4*)(uprow + k0 + soff + i);
        tmp += u;
      }
      xv[i] = tmp[0] * scale; xv[i + 1] = tmp[1] * scale;
      xv[i + 2] = tmp[2] * scale; xv[i + 3] = tmp[3] * scale;
    }
    bf16x8 wv[3][2];
#pragma unroll
    for (int s = 0; s < 3; ++s) {
      const bf16* ws = wsrc[s] + (size_t)srow * 128 + k0 + soff;
      wv[s][0] = *(const bf16x8*)ws;
      wv[s][1] = *(const bf16x8*)(ws + 8);
    }
    bf16x8 vh[2], vm[2], vl[2];
#pragma unroll
    for (int i = 0; i < 16; ++i) {
      float v = xv[i];
      bf16 h = (bf16)v; float r1 = v - (float)h;
      bf16 m = (bf16)r1; float r2 = r1 - (float)m;
      vh[i >> 3][i & 7] = h; vm[i >> 3][i & 7] = m; vl[i >> 3][i & 7] = (bf16)r2;
    }
    __syncthreads();
    *(bf16x8*)&Xs[0][sbase] = vh[0]; *(bf16x8*)&Xs[0][sbase + 8] = vh[1];
    *(bf16x8*)&Xs[1][sbase] = vm[0]; *(bf16x8*)&Xs[1][sbase + 8] = vm[1];
    *(bf16x8*)&Xs[2][sbase] = vl[0]; *(bf16x8*)&Xs[2][sbase + 8] = vl[1];
#pragma unroll
    for (int s = 0; s < 3; ++s) {
      *(bf16x8*)&Ws[s][sbase] = wv[s][0];
      *(bf16x8*)&Ws[s][sbase + 8] = wv[s][1];
    }
    __syncthreads();

    bf16x8 af[3][4], bfg[3][4];
#pragma unroll
    for (int s = 0; s < 3; ++s) {
#pragma unroll
      for (int mi = 0; mi < 4; ++mi)
        af[s][mi] = *(const bf16x8*)&Xs[s][(wr * 64 + mi * 16 + lr) * 32 + q * 8];
#pragma unroll
      for (int ni = 0; ni < 4; ++ni)
        bfg[s][ni] = *(const bf16x8*)&Ws[s][(wc * 64 + ni * 16 + lr) * 32 + q * 8];
    }
    constexpr int NT = FULL ? 6 : 3;
    constexpr int sa[6] = {0, 0, 1, 1, 0, 2};
    constexpr int sb[6] = {0, 1, 0, 1, 2, 0};
#pragma unroll
    for (int p = 0; p < NT; ++p)
#pragma unroll
      for (int mi = 0; mi < 4; ++mi)
#pragma unroll
        for (int ni = 0; ni < 4; ++ni)
          acc[mi][ni] = __builtin_amdgcn_mfma_f32_16x16x32_bf16(
              af[sa[p]][mi], bfg[sb[p]][ni], acc[mi][ni], 0, 0, 0);
  }

#pragma unroll
  for (int mi = 0; mi < 4; ++mi) {
    const int rowb = r0 + wr * 64 + mi * 16 + q * 4;
    float dnr[4];
#pragma unroll
    for (int r = 0; r < 4; ++r) dnr[r] = dnv[rowb + r];
#pragma unroll
    for (int ni = 0; ni < 4; ++ni) {
      const int col = wc * 64 + ni * 16 + lr;
      bf16x4 h4, m4, l4;
#pragma unroll
      for (int r = 0; r < 4; ++r) {
        float v = dnr[r] * acc[mi][ni][r];
        Z[(size_t)(rowb + r) * 128 + col] = v;
        Agg[(size_t)(rowb + r) * 128 + col] = 0.0f;
        bf16 h = (bf16)v; float r1 = v - (float)h;
        bf16 m = (bf16)r1; float r2 = r1 - (float)m;
        h4[r] = h; m4[r] = m; l4[r] = (bf16)r2;
      }
      *(bf16x4*)&Zht[(size_t)col * ldz + rowb] = h4;
      *(bf16x4*)&Zmt[(size_t)col * ldz + rowb] = m4;
      if (FULL) *(bf16x4*)&Zlt[(size_t)col * ldz + rowb] = l4;
    }
  }
}

// ---------------------------------------------------------------------------
// small kernels
// ---------------------------------------------------------------------------
// conv_w split (blocks 0..447) + pool_w norm (block 448) fused.
__global__ void split_w(const float* __restrict__ W, bf16* __restrict__ Wh,
                        bf16* __restrict__ Wm, bf16* __restrict__ Wl,
                        const float* __restrict__ pw, float* __restrict__ invp) {
  if (blockIdx.x == 448) {
    __shared__ float red[128];
    int t = threadIdx.x;
    if (t < 128) {
      for (int l = 0; l < 3; ++l) {
        float v = pw[l * 128 + t];
        red[t] = v * v; __syncthreads();
        for (int off = 64; off; off >>= 1) {
          if (t < off) red[t] += red[t + off];
          __syncthreads();
        }
        if (t == 0) invp[l] = 1.0f / sqrtf(red[0]);
        __syncthreads();
      }
    }
    return;
  }
  int idx = blockIdx.x * 256 + threadIdx.x;
  int l = idx >> 14, rem = idx & 16383, c = rem >> 7, k = rem & 127;
  float v = W[(l << 14) + (k << 7) + c];
  bf16 h = (bf16)v; float r1 = v - (float)h;
  bf16 m = (bf16)r1; float r2 = r1 - (float)m;
  Wh[idx] = h; Wm[idx] = m; Wl[idx] = (bf16)r2;
}

__global__ void adj2bf(const float* __restrict__ adj, bf16* __restrict__ ah,
                       float* __restrict__ dn, int n) {
  int r = blockIdx.x, t = threadIdx.x;
  const float* arow = adj + (size_t)r * n;
  bf16* orow = ah + (size_t)r * n;
  float sum = 0.f;
  for (int c4 = t * 4; c4 < n; c4 += 1024) {
    floatx4 v = *(const floatx4*)(arow + c4);
    bf16x4 o;
#pragma unroll
    for (int e = 0; e < 4; ++e) {
      float x = (c4 + e == r) ? 0.0f : v[e];
      sum += x; o[e] = (bf16)x;
    }
    *(bf16x4*)&orow[c4] = o;
  }
  __shared__ float red[256];
  red[t] = sum; __syncthreads();
  for (int off = 128; off; off >>= 1) {
    if (t < off) red[t] += red[t + off];
    __syncthreads();
  }
  if (t == 0) dn[r] = 1.0f / sqrtf(red[0] + 2.0f);
}

__global__ void dn_rows_bf(const bf16* __restrict__ A, int lda, float* __restrict__ dn,
                           int n) {
  int r = blockIdx.x, t = threadIdx.x;
  const bf16* row = A + (size_t)r * lda;
  float sum = 0.f;
  for (int c4 = t * 4; c4 < n; c4 += 1024) {
    bf16x4 v = *(const bf16x4*)&row[c4];
#pragma unroll
    for (int e = 0; e < 4; ++e) sum += (float)v[e];
  }
  __shared__ float red[256];
  red[t] = sum; __syncthreads();
  for (int off = 128; off; off >>= 1) {
    if (t < off) red[t] += red[t + off];
    __syncthreads();
  }
  if (t == 0) dn[r] = 1.0f / sqrtf(red[0] + 2.0f);
}

__global__ void dn_rows(const float* __restrict__ A, int lda, float* __restrict__ dn,
                        int n) {
  int r = blockIdx.x, t = threadIdx.x;
  const float* row = A + (size_t)r * lda;
  float sum = 0.f;
  for (int c = t; c < n; c += 256)
    if (c != r) sum += row[c];
  __shared__ float red[256];
  red[t] = sum; __syncthreads();
  for (int off = 128; off; off >>= 1) {
    if (t < off) red[t] += red[t + off];
    __syncthreads();
  }
  if (t == 0) dn[r] = 1.0f / sqrtf(red[0] + 2.0f);
}

// ---------------------------------------------------------------------------
// Fused top-k select: radix k-th largest (snapshot-fixed) + deterministic
// compaction (+inverse perm) in one single-block kernel. Threshold passes
// through LDS (sh_thr) — no global round-trip.
// ---------------------------------------------------------------------------
__device__ inline unsigned f2u(float f) {
  unsigned u = __float_as_uint(f);
  return (u & 0x80000000u) ? ~u : (u | 0x80000000u);
}
__global__ __launch_bounds__(1024) void select_kernel(
    const float* __restrict__ s, int n, int k,
    int* __restrict__ perm, float* __restrict__ vals, int* __restrict__ inv)
{
  __shared__ int hist[256];
  __shared__ int suf[256];
  __shared__ unsigned sh_prefix;
  __shared__ int sh_krem;
  __shared__ float sh_thr;
  __shared__ int cg[1024], ce[1024];
  const int t = threadIdx.x;
  if (t == 0) { sh_prefix = 0; sh_krem = k; }

  for (int round = 0; round < 4; ++round) {
    const int shift = 24 - 8 * round;
    if (t < 256) hist[t] = 0;
    __syncthreads();
    const unsigned pref = sh_prefix;   // snapshot after barrier
    const int krem = sh_krem;          // snapshot after barrier
    for (int i = t; i < n; i += 1024) {
      unsigned u = f2u(s[i]);
      if (round == 0 || (u >> (shift + 8)) == pref)
        atomicAdd(&hist[(u >> shift) & 255], 1);
    }
    __syncthreads();
    if (t < 256) suf[t] = hist[255 - t];
    __syncthreads();
    for (int off = 1; off < 256; off <<= 1) {
      int v = (t < 256 && t >= off) ? suf[t - off] : 0;
      __syncthreads();
      if (t < 256) suf[t] += v;
      __syncthreads();
    }
    // suf monotone nondecreasing -> exactly one t passes vs snapshot krem.
    if (t < 256) {
      int prev = (t == 0) ? 0 : suf[t - 1];
      if (suf[t] >= krem && prev < krem) {
        sh_prefix = (pref << 8) | (unsigned)(255 - t);
        sh_krem = krem - prev;
      }
    }
    __syncthreads();
  }
  if (t == 0) {
    unsigned u = sh_prefix;
    sh_thr = (u & 0x80000000u) ? __uint_as_float(u & 0x7fffffffu)
                               : __uint_as_float(~u);
  }
  for (int i = t; i < n; i += 1024) inv[i] = -1;
  __syncthreads();

  const float thr = sh_thr;
  const int chunk = n >> 10;
  const int beg = t * chunk;
  int g = 0, e = 0;
  for (int i = 0; i < chunk; ++i) {
    float v = s[beg + i];
    g += (v > thr); e += (v == thr);
  }
  cg[t] = g; ce[t] = e; __syncthreads();
  for (int off = 1; off < 1024; off <<= 1) {
    int a = (t >= off) ? cg[t - off] : 0;
    int b = (t >= off) ? ce[t - off] : 0;
    __syncthreads();
    cg[t] += a; ce[t] += b;
    __syncthreads();
  }
  const int total_gt = cg[1023];
  int pg = cg[t] - g;
  int pe = ce[t] - e;
  const int need = k - total_gt;
  for (int i = 0; i < chunk; ++i) {
    float v = s[beg + i];
    if (v > thr) {
      if (pg < k) { perm[pg] = beg + i; vals[pg] = v; inv[beg + i] = pg; }
      ++pg;
    } else if (v == thr) {
      if (pe < need && total_gt + pe < k) {
        perm[total_gt + pe] = beg + i; vals[total_gt + pe] = v;
        inv[beg + i] = total_gt + pe;
      }
      ++pe;
    }
  }
}

__global__ void gather_bf(const bf16* __restrict__ src, int lda,
                          const int* __restrict__ perm, bf16* __restrict__ R, int n) {
  int j = blockIdx.x, t = threadIdx.x;
  int r = perm[j];
  const bf16* s = src + (size_t)r * lda;
  bf16* o = R + (size_t)j * n;
  for (int c4 = t * 4; c4 < n; c4 += 1024) {
    bf16x4 v = *(const bf16x4*)&s[c4];
    if (r >= c4 && r < c4 + 4) v[r - c4] = (bf16)1.0f;
    *(bf16x4*)&o[c4] = v;
  }
}

__global__ void gather_f32(const float* __restrict__ src, int lda,
                           const int* __restrict__ perm, bf16* __restrict__ R, int n) {
  int j = blockIdx.x, t = threadIdx.x;
  int r = perm[j];
  const float* s = src + (size_t)r * lda;
  bf16* o = R + (size_t)j * n;
  for (int c4 = t * 4; c4 < n; c4 += 1024) {
    floatx4 v = *(const floatx4*)(s + c4);
    bf16x4 ob;
#pragma unroll
    for (int e = 0; e < 4; ++e)
      ob[e] = (c4 + e == r) ? (bf16)1.0f : (bf16)v[e];
    *(bf16x4*)&o[c4] = ob;
  }
}

// y = dn[r]*(Agg + 2*Z) + bias; relu?; write Agg in-place; BN col stats.
__global__ void gcn_post(float* __restrict__ acc, const float* __restrict__ Zf,
                         const float* __restrict__ dn, const float* __restrict__ bias,
                         float* __restrict__ stats, int relu) {
  int c = threadIdx.x;
  int r0 = blockIdx.x * 16;
  float b = bias[c];
  float s = 0.f, qq = 0.f;
  for (int i = 0; i < 16; ++i) {
    int r = r0 + i;
    float v = dn[r] * (acc[(size_t)r * 128 + c] + 2.0f * Zf[(size_t)r * 128 + c]) + b;
    if (relu) v = fmaxf(v, 0.f);
    acc[(size_t)r * 128 + c] = v;
    s += v; qq += v * v;
  }
  atomicAdd(&stats[c], s);
  atomicAdd(&stats[128 + c], qq);
}

// BN apply (coef recomputed per block) + optional fused pooling score.
__global__ void bn_apply(const float* __restrict__ H, const float* __restrict__ stats,
                         const float* __restrict__ g, const float* __restrict__ b,
                         int n, float* __restrict__ xout,
                         const float* __restrict__ pw, const float* __restrict__ invp,
                         float* __restrict__ scores) {
  int r = blockIdx.x, c = threadIdx.x;
  float m = stats[c] / n;
  float var = stats[128 + c] / n - m * m;
  float sc = g[c] / sqrtf(var + 1e-5f);
  float off = b[c] - m * sc;
  float v = sc * H[(size_t)r * 128 + c] + off;
  xout[(size_t)r * 128 + c] = v;
  if (pw) {
    __shared__ float red[128];
    red[c] = v * pw[c]; __syncthreads();
    for (int o = 64; o; o >>= 1) {
      if (c < o) red[c] += red[c + o];
      __syncthreads();
    }
    if (c == 0) scores[r] = tanhf(red[0] * invp[0]);
  }
}

// ---------------------------------------------------------------------------
extern "C" void kernel_launch(void* const* d_in, const int* in_sizes, int n_in,
                              void* d_out, int out_size, void* d_ws, size_t ws_size,
                              hipStream_t stream) {
  const float* x_in   = (const float*)d_in[0];
  const float* adj    = (const float*)d_in[1];
  const float* conv_w = (const float*)d_in[2];
  const float* conv_b = (const float*)d_in[3];
  const float* pool_w = (const float*)d_in[4];
  const float* bn_g   = (const float*)d_in[5];
  const float* bn_b   = (const float*)d_in[6];
  float* out = (float*)d_out;
  (void)in_sizes; (void)n_in; (void)out_size; (void)ws_size;

  char* p = (char*)d_ws;
  auto alloc = [&](size_t bytes) -> void* {
    void* r = (void*)p;
    p += (bytes + 255) & ~(size_t)255;
    return r;
  };
  bf16*  Ah0bf = (bf16*)alloc(4096ull * 4096 * 2);
  bf16*  A1bf  = (bf16*)alloc(2048ull * 2048 * 2);
  float* A2f   = (float*)alloc(1024ull * 1024 * 4);
  float* A3f   = (float*)alloc(512ull * 512 * 4);
  bf16*  Rbuf  = (bf16*)alloc(2048ull * 4096 * 2);
  float* Cs    = (float*)alloc(136ull * 4 * 16384 * 4);   // fp32 slices, splitZ<=4 (L3: 8 w/ 36 pairs fits)
  float* Z     = (float*)alloc(4096ull * 128 * 4);
  bf16*  Zht   = (bf16*)alloc(128ull * 4096 * 2);
  bf16*  Zmt   = (bf16*)alloc(128ull * 4096 * 2);
  bf16*  Zlt   = (bf16*)alloc(128ull * 4096 * 2);
  float* Agg   = (float*)alloc(4096ull * 128 * 4);
  float* res0  = (float*)alloc(4096ull * 128 * 4);
  float* res1  = (float*)alloc(2048ull * 128 * 4);
  float* res2  = (float*)alloc(1024ull * 128 * 4);
  float* xb0   = (float*)alloc(512ull * 128 * 4);
  float* xb1   = (float*)alloc(1024ull * 128 * 4);
  float* xb2   = (float*)alloc(2048ull * 128 * 4);
  bf16*  Wh    = (bf16*)alloc(7ull * 16384 * 2);
  bf16*  Wm    = (bf16*)alloc(7ull * 16384 * 2);
  bf16*  Wl    = (bf16*)alloc(7ull * 16384 * 2);
  float* scores = (float*)alloc(4096 * 4);
  int*   perm0 = (int*)alloc(2048 * 4);
  int*   perm1 = (int*)alloc(1024 * 4);
  int*   perm2 = (int*)alloc(512 * 4);
  int*   inv0  = (int*)alloc(4096 * 4);
  int*   inv1  = (int*)alloc(2048 * 4);
  int*   inv2  = (int*)alloc(1024 * 4);
  float* vals0 = (float*)alloc(2048 * 4);
  float* vals1 = (float*)alloc(1024 * 4);
  float* vals2 = (float*)alloc(512 * 4);
  float* dn0   = (float*)alloc(4096 * 4);
  float* dn1   = (float*)alloc(2048 * 4);
  float* dn2   = (float*)alloc(1024 * 4);
  float* dn3   = (float*)alloc(512 * 4);
  float* invp  = (float*)alloc(256);
  float* stats = (float*)alloc(1024);

  // GCN layer; (perm,vals) fuses pooling gather, (up,inv) fuses unpool add;
  // (pw,ip) fuses the next pool's score into bn_apply.
  auto gcn = [&](int nr, const bf16* Abf, const float* Af32, const float* dnv,
                 int layer, const float* xsrc, const int* perm, const float* vals,
                 const float* up, const int* inv, float* xout, int relu, int aTwo,
                 const float* pw, const float* ip, int full) {
    if (full)
      xw_split<1><<<nr / 128, 256, 0, stream>>>(
          xsrc, perm, vals, up, inv,
          Wh + layer * 16384, Wm + layer * 16384, Wl + layer * 16384, dnv,
          Z, Zht, Zmt, Zlt, nr, Agg, stats);
    else
      xw_split<0><<<nr / 128, 256, 0, stream>>>(
          xsrc, perm, vals, up, inv,
          Wh + layer * 16384, Wm + layer * 16384, Wl + layer * 16384, dnv,
          Z, Zht, Zmt, Zlt, nr, Agg, stats);
    if (Abf) {
      if (full)
        agg_bf<3><<<dim3(nr / 128, 8), 256, 0, stream>>>(
            Abf, nr, Zht, Zmt, Zlt, nr, Agg, nr / 256);
      else
        agg_bf<2><<<dim3(nr / 128, 8), 256, 0, stream>>>(
            Abf, nr, Zht, Zmt, Zlt, nr, Agg, nr / 256);
    } else {
      if (full)
        agg_split<3><<<dim3(nr / 128, 8), 256, 0, stream>>>(
            Af32, nr, Zht, Zmt, Zlt, nr, Agg, nr / 256, aTwo);
      else
        agg_split<2><<<dim3(nr / 128, 8), 256, 0, stream>>>(
            Af32, nr, Zht, Zmt, Zlt, nr, Agg, nr / 256, aTwo);
    }
    gcn_post<<<nr / 16, 128, 0, stream>>>(Agg, Z, dnv, conv_b + layer * 128, stats, relu);
    bn_apply<<<nr, 128, 0, stream>>>(Agg, stats, bn_g + layer * 128, bn_b + layer * 128,
                                     nr, xout, pw, ip, scores);
  };

  // Pool (round-11 config): fused select -> gather R=(A+I)[perm] -> R R^T
  // (fp32 slices, no atomics) -> sym_post -> dn.
  auto pool = [&](int n, const bf16* srcBf, const float* srcF32,
                  bf16* outBf, float* outF32, float* dnNew,
                  int* perm, float* vals, int* inv, int splitZ) {
    int k = n / 2, G = k / 128, pairs = G * (G + 1) / 2;
    select_kernel<<<1, 1024, 0, stream>>>(scores, n, k, perm, vals, inv);
    if (srcBf) gather_bf<<<k, 256, 0, stream>>>(srcBf, n, perm, Rbuf, n);
    else       gather_f32<<<k, 256, 0, stream>>>(srcF32, n, perm, Rbuf, n);
    gemm_sym<<<dim3(pairs, splitZ), 256, 0, stream>>>(
        Rbuf, nullptr, Cs, n, n / (splitZ * 32), G);
    sym_post<<<pairs, 128, 0, stream>>>(
        nullptr, Cs, outBf, outF32, k, G, pairs, splitZ);
    if (outBf) dn_rows_bf<<<k, 256, 0, stream>>>(outBf, k, dnNew, k);
    else       dn_rows<<<k, 256, 0, stream>>>(outF32, k, dnNew, k);
  };

  // ---- prep ----
  split_w<<<449, 256, 0, stream>>>(conv_w, Wh, Wm, Wl, pool_w, invp);
  adj2bf<<<4096, 256, 0, stream>>>(adj, Ah0bf, dn0, 4096);

  // ---- down ---- (layers 0-2 feed top-k selections: full precision)
  gcn(4096, Ah0bf, nullptr, dn0, 0, x_in, nullptr, nullptr, nullptr, nullptr,
      res0, 1, 0, pool_w + 0, invp + 0, 1);
  pool(4096, Ah0bf, nullptr, A1bf, nullptr, dn1, perm0, vals0, inv0, 4);
  gcn(2048, A1bf, nullptr, dn1, 1, res0, perm0, vals0, nullptr, nullptr,
      res1, 1, 0, pool_w + 128, invp + 1, 1);
  pool(2048, A1bf, nullptr, nullptr, A2f, dn2, perm1, vals1, inv1, 4);
  gcn(1024, nullptr, A2f, dn2, 2, res1, perm1, vals1, nullptr, nullptr,
      res2, 1, 1, pool_w + 256, invp + 2, 1);
  pool(1024, nullptr, A2f, nullptr, A3f, dn3, perm2, vals2, inv2, 8);
  // ---- layers 3-6 are value-path only: trimmed precision ----
  gcn(512, nullptr, A3f, dn3, 3, res2, perm2, vals2, nullptr, nullptr,
      xb0, 1, 1, nullptr, nullptr, 0);

  // ---- up ---- (unpool add fused into xw_split; res buffers stay intact)
  gcn(1024, nullptr, A2f, dn2, 4, res2, nullptr, nullptr, xb0, inv2,
      xb1, 1, 1, nullptr, nullptr, 0);
  gcn(2048, A1bf, nullptr, dn1, 5, res1, nullptr, nullptr, xb1, inv1,
      xb2, 1, 0, nullptr, nullptr, 0);
  gcn(4096, Ah0bf, nullptr, dn0, 6, res0, nullptr, nullptr, xb2, inv0,
      out, 0, 0, nullptr, nullptr, 0);
}

// Round 14
// 633.762 us; speedup vs baseline: 1.0327x; 1.0130x over previous
//
#include <hip/hip_runtime.h>
#include <cstdint>
#include <cstddef>

typedef __bf16 bf16;
typedef __bf16 bf16x8 __attribute__((ext_vector_type(8)));
typedef __bf16 bf16x4 __attribute__((ext_vector_type(4)));
typedef float floatx4 __attribute__((ext_vector_type(4)));

#define GLD16(gp, lp) __builtin_amdgcn_global_load_lds( \
    (const __attribute__((address_space(1))) void*)(gp), \
    (__attribute__((address_space(3))) void*)(lp), 16, 0, 0)

// ---------------------------------------------------------------------------
// Symmetric augment GEMM, M-halved for occupancy: each block computes a
// 64x128 half of an upper-tri 128x128 pair of C = R * R^T. All 4 waves share
// the 64 A-rows; each wave owns a 32-col strip of B. Slices per (pair,z),
// no atomics; bf16 slices when partials are exact ints <=256 (L1), else fp32.
// ---------------------------------------------------------------------------
__global__ __launch_bounds__(256) void gemm_sym(
    const bf16* __restrict__ R, bf16* __restrict__ CsBf, float* __restrict__ CsF,
    int n /*lda = K*/, int kIters, int G, int pairs)
{
  __shared__ __align__(16) bf16 As[64 * 32];
  __shared__ __align__(16) bf16 Bs[128 * 32];

  const int pair = blockIdx.x >> 1;
  const int half = blockIdx.x & 1;
  int rem = pair, bm = 0;
  while (rem >= G - bm) { rem -= G - bm; ++bm; }
  const int bn = bm + rem;
  const int m0 = bm * 128 + half * 64;
  const int n0 = bn * 128;

  const int t = threadIdx.x;
  const int w = t >> 6, l = t & 63;
  const int lr = l & 15, q = l >> 4;
  const int k0base = blockIdx.y * kIters * 32;

  const bf16* Ab = R + (size_t)m0 * n + k0base;
  const bf16* Bb = R + (size_t)n0 * n + k0base;
  const int srow = t >> 2;          // 0..63
  const int schunk = (t & 3) * 8;

  floatx4 acc[4][2];
#pragma unroll
  for (int i = 0; i < 4; ++i)
#pragma unroll
    for (int j = 0; j < 2; ++j) acc[i][j] = (floatx4)0.0f;

  for (int kb = 0; kb < kIters; ++kb) {
    const int k0 = kb * 32;
    __syncthreads();
    GLD16(Ab + (size_t)srow * n + k0 + schunk,        As + (size_t)t * 8);
    GLD16(Bb + (size_t)srow * n + k0 + schunk,        Bs + (size_t)t * 8);
    GLD16(Bb + (size_t)(srow + 64) * n + k0 + schunk, Bs + (size_t)(t + 256) * 8);
    __syncthreads();

    bf16x8 af[4], bfr[2];
#pragma unroll
    for (int mi = 0; mi < 4; ++mi)
      af[mi] = *(const bf16x8*)&As[(mi * 16 + lr) * 32 + q * 8];
#pragma unroll
    for (int ni = 0; ni < 2; ++ni)
      bfr[ni] = *(const bf16x8*)&Bs[(w * 32 + ni * 16 + lr) * 32 + q * 8];
#pragma unroll
    for (int mi = 0; mi < 4; ++mi)
#pragma unroll
      for (int ni = 0; ni < 2; ++ni)
        acc[mi][ni] = __builtin_amdgcn_mfma_f32_16x16x32_bf16(
            af[mi], bfr[ni], acc[mi][ni], 0, 0, 0);
  }

  const size_t so = ((size_t)blockIdx.y * pairs + pair) * 16384;
#pragma unroll
  for (int mi = 0; mi < 4; ++mi)
#pragma unroll
    for (int ni = 0; ni < 2; ++ni) {
      const int cl = w * 32 + ni * 16 + lr;
      const int rb = half * 64 + mi * 16 + q * 4;
#pragma unroll
      for (int r = 0; r < 4; ++r) {
        float v = acc[mi][ni][r];
        if (CsBf) CsBf[so + (size_t)(rb + r) * 128 + cl] = (bf16)v;
        else      CsF[so + (size_t)(rb + r) * 128 + cl] = v;
      }
    }
}

// Sum split-K slices (bf16 or fp32), write A (bf16 and/or fp32) with
// symmetric mirror, diag=0.
__global__ void sym_post(const bf16* __restrict__ CsBf, const float* __restrict__ CsF,
                         bf16* __restrict__ Abf, float* __restrict__ Af,
                         int k, int G, int pairs, int nz)
{
  int rem = blockIdx.x, bm = 0;
  while (rem >= G - bm) { rem -= G - bm; ++bm; }
  const int bn = bm + rem;
  const int i = threadIdx.x;
  const int r = bm * 128 + i;
  const size_t sbase = (size_t)blockIdx.x * 16384 + (size_t)i * 128;

  for (int jc = 0; jc < 128; jc += 16) {
    float v[16];
#pragma unroll
    for (int e = 0; e < 16; ++e) v[e] = 0.0f;
    for (int z = 0; z < nz; ++z) {
      const size_t off = sbase + (size_t)z * pairs * 16384 + jc;
      if (CsBf) {
        bf16x8 a = *(const bf16x8*)&CsBf[off];
        bf16x8 b = *(const bf16x8*)&CsBf[off + 8];
#pragma unroll
        for (int e = 0; e < 8; ++e) { v[e] += (float)a[e]; v[e + 8] += (float)b[e]; }
      } else {
#pragma unroll
        for (int e = 0; e < 16; e += 4) {
          floatx4 a = *(const floatx4*)&CsF[off + e];
#pragma unroll
          for (int j = 0; j < 4; ++j) v[e + j] += a[j];
        }
      }
    }
#pragma unroll
    for (int e = 0; e < 16; ++e) {
      const int c = bn * 128 + jc + e;
      const float val = (c == r) ? 0.0f : v[e];
      if (Abf) Abf[(size_t)r * k + c] = (bf16)val;
      if (Af)  Af[(size_t)r * k + c] = val;
      if (bm != bn) {
        if (Abf) Abf[(size_t)c * k + r] = (bf16)val;
        if (Af)  Af[(size_t)c * k + r] = val;
      }
    }
  }
}

// ---------------------------------------------------------------------------
// Aggregation (exact-int A in bf16, diag stored 0): Y += A @ Z (NP planes).
// ---------------------------------------------------------------------------
template <int NP>
__global__ __launch_bounds__(256) void agg_bf(
    const bf16* __restrict__ A, int lda,
    const bf16* __restrict__ Zh, const bf16* __restrict__ Zm, const bf16* __restrict__ Zl,
    int ldz, float* __restrict__ Y, int kIters)
{
  __shared__ __align__(16) bf16 As[128 * 32];
  __shared__ __align__(16) bf16 Zs[3][128 * 32];

  const int t = threadIdx.x;
  const int w = t >> 6, l = t & 63;
  const int wr = w >> 1, wc = w & 1;
  const int lr = l & 15, q = l >> 4;
  const int m0 = blockIdx.x * 128;
  const int k0base = blockIdx.y * kIters * 32;

  const int srow = t >> 2;
  const int schunk = (t & 3) * 8;

  floatx4 acc[4][4];
#pragma unroll
  for (int i = 0; i < 4; ++i)
#pragma unroll
    for (int j = 0; j < 4; ++j) acc[i][j] = (floatx4)0.0f;

  for (int kb = 0; kb < kIters; ++kb) {
    const int k0 = k0base + kb * 32;
    __syncthreads();
    GLD16(A + (size_t)(m0 + srow) * lda + k0 + schunk,        As + (size_t)t * 8);
    GLD16(A + (size_t)(m0 + srow + 64) * lda + k0 + schunk,   As + (size_t)(t + 256) * 8);
    GLD16(Zh + (size_t)srow * ldz + k0 + schunk,        Zs[0] + (size_t)t * 8);
    GLD16(Zh + (size_t)(srow + 64) * ldz + k0 + schunk, Zs[0] + (size_t)(t + 256) * 8);
    GLD16(Zm + (size_t)srow * ldz + k0 + schunk,        Zs[1] + (size_t)t * 8);
    GLD16(Zm + (size_t)(srow + 64) * ldz + k0 + schunk, Zs[1] + (size_t)(t + 256) * 8);
    if (NP > 2) {
      GLD16(Zl + (size_t)srow * ldz + k0 + schunk,        Zs[2] + (size_t)t * 8);
      GLD16(Zl + (size_t)(srow + 64) * ldz + k0 + schunk, Zs[2] + (size_t)(t + 256) * 8);
    }
    __syncthreads();

    bf16x8 af[4], bz[NP][4];
#pragma unroll
    for (int mi = 0; mi < 4; ++mi)
      af[mi] = *(const bf16x8*)&As[(wr * 64 + mi * 16 + lr) * 32 + q * 8];
#pragma unroll
    for (int s = 0; s < NP; ++s)
#pragma unroll
      for (int ni = 0; ni < 4; ++ni)
        bz[s][ni] = *(const bf16x8*)&Zs[s][(wc * 64 + ni * 16 + lr) * 32 + q * 8];
#pragma unroll
    for (int s = 0; s < NP; ++s)
#pragma unroll
      for (int mi = 0; mi < 4; ++mi)
#pragma unroll
        for (int ni = 0; ni < 4; ++ni)
          acc[mi][ni] = __builtin_amdgcn_mfma_f32_16x16x32_bf16(
              af[mi], bz[s][ni], acc[mi][ni], 0, 0, 0);
  }

#pragma unroll
  for (int mi = 0; mi < 4; ++mi)
#pragma unroll
    for (int ni = 0; ni < 4; ++ni) {
      const int col = wc * 64 + ni * 16 + lr;
      const int rowb = m0 + wr * 64 + mi * 16 + q * 4;
#pragma unroll
      for (int r = 0; r < 4; ++r)
        atomicAdd(&Y[(size_t)(rowb + r) * 128 + col], acc[mi][ni][r]);
    }
}

// ---------------------------------------------------------------------------
// Aggregation (fp32 A, on-the-fly 2-plane split, diag zeroed by index).
// ---------------------------------------------------------------------------
template <int NP>
__global__ __launch_bounds__(256) void agg_split(
    const float* __restrict__ A, int lda,
    const bf16* __restrict__ Zh, const bf16* __restrict__ Zm, const bf16* __restrict__ Zl,
    int ldz, float* __restrict__ Y, int kIters, int aTwo)
{
  __shared__ __align__(16) bf16 Ahs[128 * 32];
  __shared__ __align__(16) bf16 Als[128 * 32];
  __shared__ __align__(16) bf16 Zs[3][128 * 32];

  const int t = threadIdx.x;
  const int w = t >> 6, l = t & 63;
  const int wr = w >> 1, wc = w & 1;
  const int lr = l & 15, q = l >> 4;
  const int m0 = blockIdx.x * 128;
  const int k0base = blockIdx.y * kIters * 32;

  const int arow = t >> 1;
  const int acol = (t & 1) * 16;
  const int zrow = t >> 2;
  const int zchunk = (t & 3) * 8;

  floatx4 acc[4][4];
#pragma unroll
  for (int i = 0; i < 4; ++i)
#pragma unroll
    for (int j = 0; j < 4; ++j) acc[i][j] = (floatx4)0.0f;

  for (int kb = 0; kb < kIters; ++kb) {
    const int k0 = k0base + kb * 32;
    const float* asrc = A + (size_t)(m0 + arow) * lda + k0 + acol;
    floatx4 av[4];
#pragma unroll
    for (int i = 0; i < 4; ++i) av[i] = *(const floatx4*)(asrc + i * 4);

    __syncthreads();
    GLD16(Zh + (size_t)zrow * ldz + k0 + zchunk,        Zs[0] + (size_t)t * 8);
    GLD16(Zh + (size_t)(zrow + 64) * ldz + k0 + zchunk, Zs[0] + (size_t)(t + 256) * 8);
    GLD16(Zm + (size_t)zrow * ldz + k0 + zchunk,        Zs[1] + (size_t)t * 8);
    GLD16(Zm + (size_t)(zrow + 64) * ldz + k0 + zchunk, Zs[1] + (size_t)(t + 256) * 8);
    if (NP > 2) {
      GLD16(Zl + (size_t)zrow * ldz + k0 + zchunk,        Zs[2] + (size_t)t * 8);
      GLD16(Zl + (size_t)(zrow + 64) * ldz + k0 + zchunk, Zs[2] + (size_t)(t + 256) * 8);
    }

    bf16x8 ah[2], alo[2];
    const int grow = m0 + arow;
#pragma unroll
    for (int i = 0; i < 16; ++i) {
      float v = av[i >> 2][i & 3];
      if (k0 + acol + i == grow) v = 0.0f;
      bf16 h = (bf16)v;
      ah[i >> 3][i & 7] = h;
      alo[i >> 3][i & 7] = (bf16)(v - (float)h);
    }
    const int sbase = arow * 32 + acol;
    *(bf16x8*)&Ahs[sbase] = ah[0]; *(bf16x8*)&Ahs[sbase + 8] = ah[1];
    if (aTwo) { *(bf16x8*)&Als[sbase] = alo[0]; *(bf16x8*)&Als[sbase + 8] = alo[1]; }
    __syncthreads();

    bf16x8 afh[4], afl[4], bz[NP][4];
#pragma unroll
    for (int mi = 0; mi < 4; ++mi)
      afh[mi] = *(const bf16x8*)&Ahs[(wr * 64 + mi * 16 + lr) * 32 + q * 8];
#pragma unroll
    for (int s = 0; s < NP; ++s)
#pragma unroll
      for (int ni = 0; ni < 4; ++ni)
        bz[s][ni] = *(const bf16x8*)&Zs[s][(wc * 64 + ni * 16 + lr) * 32 + q * 8];
#pragma unroll
    for (int s = 0; s < NP; ++s)
#pragma unroll
      for (int mi = 0; mi < 4; ++mi)
#pragma unroll
        for (int ni = 0; ni < 4; ++ni)
          acc[mi][ni] = __builtin_amdgcn_mfma_f32_16x16x32_bf16(
              afh[mi], bz[s][ni], acc[mi][ni], 0, 0, 0);
    if (aTwo) {
#pragma unroll
      for (int mi = 0; mi < 4; ++mi)
        afl[mi] = *(const bf16x8*)&Als[(wr * 64 + mi * 16 + lr) * 32 + q * 8];
      constexpr int NL = (NP > 2) ? 2 : 1;
#pragma unroll
      for (int s = 0; s < NL; ++s)
#pragma unroll
        for (int mi = 0; mi < 4; ++mi)
#pragma unroll
          for (int ni = 0; ni < 4; ++ni)
            acc[mi][ni] = __builtin_amdgcn_mfma_f32_16x16x32_bf16(
                afl[mi], bz[s][ni], acc[mi][ni], 0, 0, 0);
    }
  }

#pragma unroll
  for (int mi = 0; mi < 4; ++mi)
#pragma unroll
    for (int ni = 0; ni < 4; ++ni) {
      const int col = wc * 64 + ni * 16 + lr;
      const int rowb = m0 + wr * 64 + mi * 16 + q * 4;
#pragma unroll
      for (int r = 0; r < 4; ++r)
        atomicAdd(&Y[(size_t)(rowb + r) * 128 + col], acc[mi][ni][r]);
    }
}

// ---------------------------------------------------------------------------
// Z[nr,128] = dn ⊙ (x @ W); x row = X[perm[row]]*vals[row]  (pool fusion)
//                       or  X[row] + up[inv[row]]            (unpool fusion)
// FULL=1: 6-term (2^-24), 3 planes. FULL=0: 3-term (2^-16), 2 planes.
// ---------------------------------------------------------------------------
template <int FULL>
__global__ __launch_bounds__(256) void xw_split(
    const float* __restrict__ X, const int* __restrict__ perm,
    const float* __restrict__ vals,
    const float* __restrict__ up, const int* __restrict__ inv,
    const bf16* __restrict__ Wh, const bf16* __restrict__ Wm, const bf16* __restrict__ Wl,
    const float* __restrict__ dnv, float* __restrict__ Z,
    bf16* __restrict__ Zht, bf16* __restrict__ Zmt, bf16* __restrict__ Zlt, int ldz,
    float* __restrict__ Agg, float* __restrict__ stats)
{
  __shared__ __align__(16) bf16 Xs[3][128 * 32];
  __shared__ __align__(16) bf16 Ws[3][128 * 32];

  const int t = threadIdx.x;
  if (blockIdx.x == 0) stats[t] = 0.0f;

  const int w = t >> 6, l = t & 63;
  const int wr = w >> 1, wc = w & 1;
  const int lr = l & 15, q = l >> 4;
  const int r0 = blockIdx.x * 128;

  const int srow = t >> 1;
  const int soff = (t & 1) * 16;
  const int sbase = srow * 32 + soff;

  const int row = r0 + srow;
  int grow = row;
  float scale = 1.0f;
  if (perm) { grow = perm[row]; scale = vals[row]; }
  const float* xrow = X + (size_t)grow * 128;
  const float* uprow = nullptr;
  if (up) { int j = inv[row]; if (j >= 0) uprow = up + (size_t)j * 128; }

  floatx4 acc[4][4];
#pragma unroll
  for (int i = 0; i < 4; ++i)
#pragma unroll
    for (int j = 0; j < 4; ++j) acc[i][j] = (floatx4)0.0f;

  const bf16* wsrc[3] = {Wh, Wm, Wl};

  for (int ks = 0; ks < 4; ++ks) {
    const int k0 = ks * 32;
    float xv[16];
#pragma unroll
    for (int i = 0; i < 16; i += 4) {
      floatx4 tmp = *(const floatx4*)(xrow + k0 + soff + i);
      if (uprow) {
        floatx4 u = *(const floatx4*)(uprow + k0 + soff + i);
        tmp += u;
      }
      xv[i] = tmp[0] * scale; xv[i + 1] = tmp[1] * scale;
      xv[i + 2] = tmp[2] * scale; xv[i + 3] = tmp[3] * scale;
    }
    bf16x8 wv[3][2];
#pragma unroll
    for (int s = 0; s < 3; ++s) {
      const bf16* ws = wsrc[s] + (size_t)srow * 128 + k0 + soff;
      wv[s][0] = *(const bf16x8*)ws;
      wv[s][1] = *(const bf16x8*)(ws + 8);
    }
    bf16x8 vh[2], vm[2], vl[2];
#pragma unroll
    for (int i = 0; i < 16; ++i) {
      float v = xv[i];
      bf16 h = (bf16)v; float r1 = v - (float)h;
      bf16 m = (bf16)r1; float r2 = r1 - (float)m;
      vh[i >> 3][i & 7] = h; vm[i >> 3][i & 7] = m; vl[i >> 3][i & 7] = (bf16)r2;
    }
    __syncthreads();
    *(bf16x8*)&Xs[0][sbase] = vh[0]; *(bf16x8*)&Xs[0][sbase + 8] = vh[1];
    *(bf16x8*)&Xs[1][sbase] = vm[0]; *(bf16x8*)&Xs[1][sbase + 8] = vm[1];
    *(bf16x8*)&Xs[2][sbase] = vl[0]; *(bf16x8*)&Xs[2][sbase + 8] = vl[1];
#pragma unroll
    for (int s = 0; s < 3; ++s) {
      *(bf16x8*)&Ws[s][sbase] = wv[s][0];
      *(bf16x8*)&Ws[s][sbase + 8] = wv[s][1];
    }
    __syncthreads();

    bf16x8 af[3][4], bfg[3][4];
#pragma unroll
    for (int s = 0; s < 3; ++s) {
#pragma unroll
      for (int mi = 0; mi < 4; ++mi)
        af[s][mi] = *(const bf16x8*)&Xs[s][(wr * 64 + mi * 16 + lr) * 32 + q * 8];
#pragma unroll
      for (int ni = 0; ni < 4; ++ni)
        bfg[s][ni] = *(const bf16x8*)&Ws[s][(wc * 64 + ni * 16 + lr) * 32 + q * 8];
    }
    constexpr int NT = FULL ? 6 : 3;
    constexpr int sa[6] = {0, 0, 1, 1, 0, 2};
    constexpr int sb[6] = {0, 1, 0, 1, 2, 0};
#pragma unroll
    for (int p = 0; p < NT; ++p)
#pragma unroll
      for (int mi = 0; mi < 4; ++mi)
#pragma unroll
        for (int ni = 0; ni < 4; ++ni)
          acc[mi][ni] = __builtin_amdgcn_mfma_f32_16x16x32_bf16(
              af[sa[p]][mi], bfg[sb[p]][ni], acc[mi][ni], 0, 0, 0);
  }

#pragma unroll
  for (int mi = 0; mi < 4; ++mi) {
    const int rowb = r0 + wr * 64 + mi * 16 + q * 4;
    float dnr[4];
#pragma unroll
    for (int r = 0; r < 4; ++r) dnr[r] = dnv[rowb + r];
#pragma unroll
    for (int ni = 0; ni < 4; ++ni) {
      const int col = wc * 64 + ni * 16 + lr;
      bf16x4 h4, m4, l4;
#pragma unroll
      for (int r = 0; r < 4; ++r) {
        float v = dnr[r] * acc[mi][ni][r];
        Z[(size_t)(rowb + r) * 128 + col] = v;
        Agg[(size_t)(rowb + r) * 128 + col] = 0.0f;
        bf16 h = (bf16)v; float r1 = v - (float)h;
        bf16 m = (bf16)r1; float r2 = r1 - (float)m;
        h4[r] = h; m4[r] = m; l4[r] = (bf16)r2;
      }
      *(bf16x4*)&Zht[(size_t)col * ldz + rowb] = h4;
      *(bf16x4*)&Zmt[(size_t)col * ldz + rowb] = m4;
      if (FULL) *(bf16x4*)&Zlt[(size_t)col * ldz + rowb] = l4;
    }
  }
}

// ---------------------------------------------------------------------------
// Fused prep: blocks [0,4096) adj->bf16+dn; [4096,4544) conv_w 3-way split;
// block 4544 pool_w inverse norms.
// ---------------------------------------------------------------------------
__global__ void prep_all(const float* __restrict__ adj, bf16* __restrict__ ah,
                         float* __restrict__ dn, int n,
                         const float* __restrict__ W, bf16* __restrict__ Wh,
                         bf16* __restrict__ Wm, bf16* __restrict__ Wl,
                         const float* __restrict__ pw, float* __restrict__ invp) {
  const int bid = blockIdx.x;
  const int t = threadIdx.x;
  if (bid < 4096) {
    int r = bid;
    const float* arow = adj + (size_t)r * n;
    bf16* orow = ah + (size_t)r * n;
    float sum = 0.f;
    for (int c4 = t * 4; c4 < n; c4 += 1024) {
      floatx4 v = *(const floatx4*)(arow + c4);
      bf16x4 o;
#pragma unroll
      for (int e = 0; e < 4; ++e) {
        float x = (c4 + e == r) ? 0.0f : v[e];
        sum += x; o[e] = (bf16)x;
      }
      *(bf16x4*)&orow[c4] = o;
    }
    __shared__ float red[256];
    red[t] = sum; __syncthreads();
    for (int off = 128; off; off >>= 1) {
      if (t < off) red[t] += red[t + off];
      __syncthreads();
    }
    if (t == 0) dn[r] = 1.0f / sqrtf(red[0] + 2.0f);
  } else if (bid < 4544) {
    int idx = (bid - 4096) * 256 + t;
    int l = idx >> 14, rem = idx & 16383, c = rem >> 7, k = rem & 127;
    float v = W[(l << 14) + (k << 7) + c];
    bf16 h = (bf16)v; float r1 = v - (float)h;
    bf16 m = (bf16)r1; float r2 = r1 - (float)m;
    Wh[idx] = h; Wm[idx] = m; Wl[idx] = (bf16)r2;
  } else {
    __shared__ float red[128];
    if (t < 128) {
      for (int l = 0; l < 3; ++l) {
        float v = pw[l * 128 + t];
        red[t] = v * v; __syncthreads();
        for (int off = 64; off; off >>= 1) {
          if (t < off) red[t] += red[t + off];
          __syncthreads();
        }
        if (t == 0) invp[l] = 1.0f / sqrtf(red[0]);
        __syncthreads();
      }
    }
  }
}

__global__ void dn_rows_bf(const bf16* __restrict__ A, int lda, float* __restrict__ dn,
                           int n) {
  int r = blockIdx.x, t = threadIdx.x;
  const bf16* row = A + (size_t)r * lda;
  float sum = 0.f;
  for (int c4 = t * 4; c4 < n; c4 += 1024) {
    bf16x4 v = *(const bf16x4*)&row[c4];
#pragma unroll
    for (int e = 0; e < 4; ++e) sum += (float)v[e];
  }
  __shared__ float red[256];
  red[t] = sum; __syncthreads();
  for (int off = 128; off; off >>= 1) {
    if (t < off) red[t] += red[t + off];
    __syncthreads();
  }
  if (t == 0) dn[r] = 1.0f / sqrtf(red[0] + 2.0f);
}

__global__ void dn_rows(const float* __restrict__ A, int lda, float* __restrict__ dn,
                        int n) {
  int r = blockIdx.x, t = threadIdx.x;
  const float* row = A + (size_t)r * lda;
  float sum = 0.f;
  for (int c = t; c < n; c += 256)
    if (c != r) sum += row[c];
  __shared__ float red[256];
  red[t] = sum; __syncthreads();
  for (int off = 128; off; off >>= 1) {
    if (t < off) red[t] += red[t + off];
    __syncthreads();
  }
  if (t == 0) dn[r] = 1.0f / sqrtf(red[0] + 2.0f);
}

// ---------------------------------------------------------------------------
// Fused top-k select: radix k-th largest (snapshot-fixed) + deterministic
// compaction (+inverse perm) in one single-block kernel.
// ---------------------------------------------------------------------------
__device__ inline unsigned f2u(float f) {
  unsigned u = __float_as_uint(f);
  return (u & 0x80000000u) ? ~u : (u | 0x80000000u);
}
__global__ __launch_bounds__(1024) void select_kernel(
    const float* __restrict__ s, int n, int k,
    int* __restrict__ perm, float* __restrict__ vals, int* __restrict__ inv)
{
  __shared__ int hist[256];
  __shared__ int suf[256];
  __shared__ unsigned sh_prefix;
  __shared__ int sh_krem;
  __shared__ float sh_thr;
  __shared__ int cg[1024], ce[1024];
  const int t = threadIdx.x;
  if (t == 0) { sh_prefix = 0; sh_krem = k; }

  for (int round = 0; round < 4; ++round) {
    const int shift = 24 - 8 * round;
    if (t < 256) hist[t] = 0;
    __syncthreads();
    const unsigned pref = sh_prefix;
    const int krem = sh_krem;
    for (int i = t; i < n; i += 1024) {
      unsigned u = f2u(s[i]);
      if (round == 0 || (u >> (shift + 8)) == pref)
        atomicAdd(&hist[(u >> shift) & 255], 1);
    }
    __syncthreads();
    if (t < 256) suf[t] = hist[255 - t];
    __syncthreads();
    for (int off = 1; off < 256; off <<= 1) {
      int v = (t < 256 && t >= off) ? suf[t - off] : 0;
      __syncthreads();
      if (t < 256) suf[t] += v;
      __syncthreads();
    }
    if (t < 256) {
      int prev = (t == 0) ? 0 : suf[t - 1];
      if (suf[t] >= krem && prev < krem) {
        sh_prefix = (pref << 8) | (unsigned)(255 - t);
        sh_krem = krem - prev;
      }
    }
    __syncthreads();
  }
  if (t == 0) {
    unsigned u = sh_prefix;
    sh_thr = (u & 0x80000000u) ? __uint_as_float(u & 0x7fffffffu)
                               : __uint_as_float(~u);
  }
  for (int i = t; i < n; i += 1024) inv[i] = -1;
  __syncthreads();

  const float thr = sh_thr;
  const int chunk = n >> 10;
  const int beg = t * chunk;
  int g = 0, e = 0;
  for (int i = 0; i < chunk; ++i) {
    float v = s[beg + i];
    g += (v > thr); e += (v == thr);
  }
  cg[t] = g; ce[t] = e; __syncthreads();
  for (int off = 1; off < 1024; off <<= 1) {
    int a = (t >= off) ? cg[t - off] : 0;
    int b = (t >= off) ? ce[t - off] : 0;
    __syncthreads();
    cg[t] += a; ce[t] += b;
    __syncthreads();
  }
  const int total_gt = cg[1023];
  int pg = cg[t] - g;
  int pe = ce[t] - e;
  const int need = k - total_gt;
  for (int i = 0; i < chunk; ++i) {
    float v = s[beg + i];
    if (v > thr) {
      if (pg < k) { perm[pg] = beg + i; vals[pg] = v; inv[beg + i] = pg; }
      ++pg;
    } else if (v == thr) {
      if (pe < need && total_gt + pe < k) {
        perm[total_gt + pe] = beg + i; vals[total_gt + pe] = v;
        inv[beg + i] = total_gt + pe;
      }
      ++pe;
    }
  }
}

__global__ void gather_bf(const bf16* __restrict__ src, int lda,
                          const int* __restrict__ perm, bf16* __restrict__ R, int n) {
  int j = blockIdx.x, t = threadIdx.x;
  int r = perm[j];
  const bf16* s = src + (size_t)r * lda;
  bf16* o = R + (size_t)j * n;
  for (int c4 = t * 4; c4 < n; c4 += 1024) {
    bf16x4 v = *(const bf16x4*)&s[c4];
    if (r >= c4 && r < c4 + 4) v[r - c4] = (bf16)1.0f;
    *(bf16x4*)&o[c4] = v;
  }
}

__global__ void gather_f32(const float* __restrict__ src, int lda,
                           const int* __restrict__ perm, bf16* __restrict__ R, int n) {
  int j = blockIdx.x, t = threadIdx.x;
  int r = perm[j];
  const float* s = src + (size_t)r * lda;
  bf16* o = R + (size_t)j * n;
  for (int c4 = t * 4; c4 < n; c4 += 1024) {
    floatx4 v = *(const floatx4*)(s + c4);
    bf16x4 ob;
#pragma unroll
    for (int e = 0; e < 4; ++e)
      ob[e] = (c4 + e == r) ? (bf16)1.0f : (bf16)v[e];
    *(bf16x4*)&o[c4] = ob;
  }
}

// y = dn[r]*(Agg + 2*Z) + bias; relu?; write Agg in-place; BN col stats.
__global__ void gcn_post(float* __restrict__ acc, const float* __restrict__ Zf,
                         const float* __restrict__ dn, const float* __restrict__ bias,
                         float* __restrict__ stats, int relu) {
  int c = threadIdx.x;
  int r0 = blockIdx.x * 16;
  float b = bias[c];
  float s = 0.f, qq = 0.f;
  for (int i = 0; i < 16; ++i) {
    int r = r0 + i;
    float v = dn[r] * (acc[(size_t)r * 128 + c] + 2.0f * Zf[(size_t)r * 128 + c]) + b;
    if (relu) v = fmaxf(v, 0.f);
    acc[(size_t)r * 128 + c] = v;
    s += v; qq += v * v;
  }
  atomicAdd(&stats[c], s);
  atomicAdd(&stats[128 + c], qq);
}

// BN apply (coef recomputed per block) + optional fused pooling score.
__global__ void bn_apply(const float* __restrict__ H, const float* __restrict__ stats,
                         const float* __restrict__ g, const float* __restrict__ b,
                         int n, float* __restrict__ xout,
                         const float* __restrict__ pw, const float* __restrict__ invp,
                         float* __restrict__ scores) {
  int r = blockIdx.x, c = threadIdx.x;
  float m = stats[c] / n;
  float var = stats[128 + c] / n - m * m;
  float sc = g[c] / sqrtf(var + 1e-5f);
  float off = b[c] - m * sc;
  float v = sc * H[(size_t)r * 128 + c] + off;
  xout[(size_t)r * 128 + c] = v;
  if (pw) {
    __shared__ float red[128];
    red[c] = v * pw[c]; __syncthreads();
    for (int o = 64; o; o >>= 1) {
      if (c < o) red[c] += red[c + o];
      __syncthreads();
    }
    if (c == 0) scores[r] = tanhf(red[0] * invp[0]);
  }
}

// ---------------------------------------------------------------------------
extern "C" void kernel_launch(void* const* d_in, const int* in_sizes, int n_in,
                              void* d_out, int out_size, void* d_ws, size_t ws_size,
                              hipStream_t stream) {
  const float* x_in   = (const float*)d_in[0];
  const float* adj    = (const float*)d_in[1];
  const float* conv_w = (const float*)d_in[2];
  const float* conv_b = (const float*)d_in[3];
  const float* pool_w = (const float*)d_in[4];
  const float* bn_g   = (const float*)d_in[5];
  const float* bn_b   = (const float*)d_in[6];
  float* out = (float*)d_out;
  (void)in_sizes; (void)n_in; (void)out_size; (void)ws_size;

  char* p = (char*)d_ws;
  auto alloc = [&](size_t bytes) -> void* {
    void* r = (void*)p;
    p += (bytes + 255) & ~(size_t)255;
    return r;
  };
  bf16*  Ah0bf = (bf16*)alloc(4096ull * 4096 * 2);
  bf16*  A1bf  = (bf16*)alloc(2048ull * 2048 * 2);
  float* A2f   = (float*)alloc(1024ull * 1024 * 4);
  float* A3f   = (float*)alloc(512ull * 512 * 4);
  bf16*  Rbuf  = (bf16*)alloc(2048ull * 4096 * 2);
  void*  Cs    = alloc(136ull * 4 * 16384 * 4);   // L1 bf16 (17.8MB) / L2,L3 fp32
  float* Z     = (float*)alloc(4096ull * 128 * 4);
  bf16*  Zht   = (bf16*)alloc(128ull * 4096 * 2);
  bf16*  Zmt   = (bf16*)alloc(128ull * 4096 * 2);
  bf16*  Zlt   = (bf16*)alloc(128ull * 4096 * 2);
  float* Agg   = (float*)alloc(4096ull * 128 * 4);
  float* res0  = (float*)alloc(4096ull * 128 * 4);
  float* res1  = (float*)alloc(2048ull * 128 * 4);
  float* res2  = (float*)alloc(1024ull * 128 * 4);
  float* xb0   = (float*)alloc(512ull * 128 * 4);
  float* xb1   = (float*)alloc(1024ull * 128 * 4);
  float* xb2   = (float*)alloc(2048ull * 128 * 4);
  bf16*  Wh    = (bf16*)alloc(7ull * 16384 * 2);
  bf16*  Wm    = (bf16*)alloc(7ull * 16384 * 2);
  bf16*  Wl    = (bf16*)alloc(7ull * 16384 * 2);
  float* scores = (float*)alloc(4096 * 4);
  int*   perm0 = (int*)alloc(2048 * 4);
  int*   perm1 = (int*)alloc(1024 * 4);
  int*   perm2 = (int*)alloc(512 * 4);
  int*   inv0  = (int*)alloc(4096 * 4);
  int*   inv1  = (int*)alloc(2048 * 4);
  int*   inv2  = (int*)alloc(1024 * 4);
  float* vals0 = (float*)alloc(2048 * 4);
  float* vals1 = (float*)alloc(1024 * 4);
  float* vals2 = (float*)alloc(512 * 4);
  float* dn0   = (float*)alloc(4096 * 4);
  float* dn1   = (float*)alloc(2048 * 4);
  float* dn2   = (float*)alloc(1024 * 4);
  float* dn3   = (float*)alloc(512 * 4);
  float* invp  = (float*)alloc(256);
  float* stats = (float*)alloc(1024);

  auto gcn = [&](int nr, const bf16* Abf, const float* Af32, const float* dnv,
                 int layer, const float* xsrc, const int* perm, const float* vals,
                 const float* up, const int* inv, float* xout, int relu, int aTwo,
                 const float* pw, const float* ip, int full) {
    if (full)
      xw_split<1><<<nr / 128, 256, 0, stream>>>(
          xsrc, perm, vals, up, inv,
          Wh + layer * 16384, Wm + layer * 16384, Wl + layer * 16384, dnv,
          Z, Zht, Zmt, Zlt, nr, Agg, stats);
    else
      xw_split<0><<<nr / 128, 256, 0, stream>>>(
          xsrc, perm, vals, up, inv,
          Wh + layer * 16384, Wm + layer * 16384, Wl + layer * 16384, dnv,
          Z, Zht, Zmt, Zlt, nr, Agg, stats);
    if (Abf) {
      if (full)
        agg_bf<3><<<dim3(nr / 128, 8), 256, 0, stream>>>(
            Abf, nr, Zht, Zmt, Zlt, nr, Agg, nr / 256);
      else
        agg_bf<2><<<dim3(nr / 128, 8), 256, 0, stream>>>(
            Abf, nr, Zht, Zmt, Zlt, nr, Agg, nr / 256);
    } else {
      if (full)
        agg_split<3><<<dim3(nr / 128, 8), 256, 0, stream>>>(
            Af32, nr, Zht, Zmt, Zlt, nr, Agg, nr / 256, aTwo);
      else
        agg_split<2><<<dim3(nr / 128, 8), 256, 0, stream>>>(
            Af32, nr, Zht, Zmt, Zlt, nr, Agg, nr / 256, aTwo);
    }
    gcn_post<<<nr / 16, 128, 0, stream>>>(Agg, Z, dnv, conv_b + layer * 128, stats, relu);
    bn_apply<<<nr, 128, 0, stream>>>(Agg, stats, bn_g + layer * 128, bn_b + layer * 128,
                                     nr, xout, pw, ip, scores);
  };

  // Pool: fused select -> gather R=(A+I)[perm] -> M-halved R R^T (slices, no
  // atomics; bf16 slices at L1 where partials are exact ints) -> sym_post -> dn.
  auto pool = [&](int n, const bf16* srcBf, const float* srcF32,
                  bf16* outBf, float* outF32, float* dnNew,
                  int* perm, float* vals, int* inv, int splitZ, int sliceBf) {
    int k = n / 2, G = k / 128, pairs = G * (G + 1) / 2;
    select_kernel<<<1, 1024, 0, stream>>>(scores, n, k, perm, vals, inv);
    if (srcBf) gather_bf<<<k, 256, 0, stream>>>(srcBf, n, perm, Rbuf, n);
    else       gather_f32<<<k, 256, 0, stream>>>(srcF32, n, perm, Rbuf, n);
    gemm_sym<<<dim3(pairs * 2, splitZ), 256, 0, stream>>>(
        Rbuf, sliceBf ? (bf16*)Cs : nullptr, sliceBf ? nullptr : (float*)Cs,
        n, n / (splitZ * 32), G, pairs);
    sym_post<<<pairs, 128, 0, stream>>>(
        sliceBf ? (const bf16*)Cs : nullptr, sliceBf ? nullptr : (const float*)Cs,
        outBf, outF32, k, G, pairs, splitZ);
    if (outBf) dn_rows_bf<<<k, 256, 0, stream>>>(outBf, k, dnNew, k);
    else       dn_rows<<<k, 256, 0, stream>>>(outF32, k, dnNew, k);
  };

  // ---- prep (one launch) ----
  prep_all<<<4545, 256, 0, stream>>>(adj, Ah0bf, dn0, 4096,
                                     conv_w, Wh, Wm, Wl, pool_w, invp);

  // ---- down ---- (layers 0-2 feed top-k selections: full precision)
  gcn(4096, Ah0bf, nullptr, dn0, 0, x_in, nullptr, nullptr, nullptr, nullptr,
      res0, 1, 0, pool_w + 0, invp + 0, 1);
  pool(4096, Ah0bf, nullptr, A1bf, nullptr, dn1, perm0, vals0, inv0, 4, 1);
  gcn(2048, A1bf, nullptr, dn1, 1, res0, perm0, vals0, nullptr, nullptr,
      res1, 1, 0, pool_w + 128, invp + 1, 1);
  pool(2048, A1bf, nullptr, nullptr, A2f, dn2, perm1, vals1, inv1, 4, 0);
  gcn(1024, nullptr, A2f, dn2, 2, res1, perm1, vals1, nullptr, nullptr,
      res2, 1, 1, pool_w + 256, invp + 2, 1);
  pool(1024, nullptr, A2f, nullptr, A3f, dn3, perm2, vals2, inv2, 8, 0);
  // ---- layers 3-6 are value-path only: trimmed precision ----
  gcn(512, nullptr, A3f, dn3, 3, res2, perm2, vals2, nullptr, nullptr,
      xb0, 1, 1, nullptr, nullptr, 0);

  // ---- up ---- (unpool add fused into xw_split; res buffers stay intact)
  gcn(1024, nullptr, A2f, dn2, 4, res2, nullptr, nullptr, xb0, inv2,
      xb1, 1, 1, nullptr, nullptr, 0);
  gcn(2048, A1bf, nullptr, dn1, 5, res1, nullptr, nullptr, xb1, inv1,
      xb2, 1, 0, nullptr, nullptr, 0);
  gcn(4096, Ah0bf, nullptr, dn0, 6, res0, nullptr, nullptr, xb2, inv0,
      out, 0, 0, nullptr, nullptr, 0);
}

// Round 15
// 611.770 us; speedup vs baseline: 1.0698x; 1.0359x over previous
//
#include <hip/hip_runtime.h>
#include <cstdint>
#include <cstddef>

typedef __bf16 bf16;
typedef __bf16 bf16x8 __attribute__((ext_vector_type(8)));
typedef __bf16 bf16x4 __attribute__((ext_vector_type(4)));
typedef float floatx4 __attribute__((ext_vector_type(4)));

#define GLD16(gp, lp) __builtin_amdgcn_global_load_lds( \
    (const __attribute__((address_space(1))) void*)(gp), \
    (__attribute__((address_space(3))) void*)(lp), 16, 0, 0)

// ---------------------------------------------------------------------------
// Symmetric augment GEMM, M-halved: 64x128 half of an upper-tri pair of
// C = R * R^T. Slices per (pair,z), no atomics; bf16 slices at L1.
// ---------------------------------------------------------------------------
__global__ __launch_bounds__(256) void gemm_sym(
    const bf16* __restrict__ R, bf16* __restrict__ CsBf, float* __restrict__ CsF,
    int n /*lda = K*/, int kIters, int G, int pairs)
{
  __shared__ __align__(16) bf16 As[64 * 32];
  __shared__ __align__(16) bf16 Bs[128 * 32];

  const int pair = blockIdx.x >> 1;
  const int half = blockIdx.x & 1;
  int rem = pair, bm = 0;
  while (rem >= G - bm) { rem -= G - bm; ++bm; }
  const int bn = bm + rem;
  const int m0 = bm * 128 + half * 64;
  const int n0 = bn * 128;

  const int t = threadIdx.x;
  const int w = t >> 6, l = t & 63;
  const int lr = l & 15, q = l >> 4;
  const int k0base = blockIdx.y * kIters * 32;

  const bf16* Ab = R + (size_t)m0 * n + k0base;
  const bf16* Bb = R + (size_t)n0 * n + k0base;
  const int srow = t >> 2;
  const int schunk = (t & 3) * 8;

  floatx4 acc[4][2];
#pragma unroll
  for (int i = 0; i < 4; ++i)
#pragma unroll
    for (int j = 0; j < 2; ++j) acc[i][j] = (floatx4)0.0f;

  for (int kb = 0; kb < kIters; ++kb) {
    const int k0 = kb * 32;
    __syncthreads();
    GLD16(Ab + (size_t)srow * n + k0 + schunk,        As + (size_t)t * 8);
    GLD16(Bb + (size_t)srow * n + k0 + schunk,        Bs + (size_t)t * 8);
    GLD16(Bb + (size_t)(srow + 64) * n + k0 + schunk, Bs + (size_t)(t + 256) * 8);
    __syncthreads();

    bf16x8 af[4], bfr[2];
#pragma unroll
    for (int mi = 0; mi < 4; ++mi)
      af[mi] = *(const bf16x8*)&As[(mi * 16 + lr) * 32 + q * 8];
#pragma unroll
    for (int ni = 0; ni < 2; ++ni)
      bfr[ni] = *(const bf16x8*)&Bs[(w * 32 + ni * 16 + lr) * 32 + q * 8];
#pragma unroll
    for (int mi = 0; mi < 4; ++mi)
#pragma unroll
      for (int ni = 0; ni < 2; ++ni)
        acc[mi][ni] = __builtin_amdgcn_mfma_f32_16x16x32_bf16(
            af[mi], bfr[ni], acc[mi][ni], 0, 0, 0);
  }

  const size_t so = ((size_t)blockIdx.y * pairs + pair) * 16384;
#pragma unroll
  for (int mi = 0; mi < 4; ++mi)
#pragma unroll
    for (int ni = 0; ni < 2; ++ni) {
      const int cl = w * 32 + ni * 16 + lr;
      const int rb = half * 64 + mi * 16 + q * 4;
#pragma unroll
      for (int r = 0; r < 4; ++r) {
        float v = acc[mi][ni][r];
        if (CsBf) CsBf[so + (size_t)(rb + r) * 128 + cl] = (bf16)v;
        else      CsF[so + (size_t)(rb + r) * 128 + cl] = v;
      }
    }
}

// Sum split-K slices (bf16 or fp32), write A with symmetric mirror, diag=0.
__global__ void sym_post(const bf16* __restrict__ CsBf, const float* __restrict__ CsF,
                         bf16* __restrict__ Abf, float* __restrict__ Af,
                         int k, int G, int pairs, int nz)
{
  int rem = blockIdx.x, bm = 0;
  while (rem >= G - bm) { rem -= G - bm; ++bm; }
  const int bn = bm + rem;
  const int i = threadIdx.x;
  const int r = bm * 128 + i;
  const size_t sbase = (size_t)blockIdx.x * 16384 + (size_t)i * 128;

  for (int jc = 0; jc < 128; jc += 16) {
    float v[16];
#pragma unroll
    for (int e = 0; e < 16; ++e) v[e] = 0.0f;
    for (int z = 0; z < nz; ++z) {
      const size_t off = sbase + (size_t)z * pairs * 16384 + jc;
      if (CsBf) {
        bf16x8 a = *(const bf16x8*)&CsBf[off];
        bf16x8 b = *(const bf16x8*)&CsBf[off + 8];
#pragma unroll
        for (int e = 0; e < 8; ++e) { v[e] += (float)a[e]; v[e + 8] += (float)b[e]; }
      } else {
#pragma unroll
        for (int e = 0; e < 16; e += 4) {
          floatx4 a = *(const floatx4*)&CsF[off + e];
#pragma unroll
          for (int j = 0; j < 4; ++j) v[e + j] += a[j];
        }
      }
    }
#pragma unroll
    for (int e = 0; e < 16; ++e) {
      const int c = bn * 128 + jc + e;
      const float val = (c == r) ? 0.0f : v[e];
      if (Abf) Abf[(size_t)r * k + c] = (bf16)val;
      if (Af)  Af[(size_t)r * k + c] = val;
      if (bm != bn) {
        if (Abf) Abf[(size_t)c * k + r] = (bf16)val;
        if (Af)  Af[(size_t)c * k + r] = val;
      }
    }
  }
}

// ---------------------------------------------------------------------------
// Aggregation M-halved (exact-int A in bf16, diag 0): Y += A @ Z (NP planes).
// 64 A-rows/block; quadrant wave map (wr=w>>1 rows, wc=w&1 cols); acc[2][4].
// Grid (nr/64, splitK) doubles blocks vs the M=128 form (occupancy fix).
// ---------------------------------------------------------------------------
template <int NP>
__global__ __launch_bounds__(256) void agg_bf(
    const bf16* __restrict__ A, int lda,
    const bf16* __restrict__ Zh, const bf16* __restrict__ Zm, const bf16* __restrict__ Zl,
    int ldz, float* __restrict__ Y, int kIters)
{
  __shared__ __align__(16) bf16 As[64 * 32];
  __shared__ __align__(16) bf16 Zs[NP][128 * 32];

  const int t = threadIdx.x;
  const int w = t >> 6, l = t & 63;
  const int wr = w >> 1, wc = w & 1;
  const int lr = l & 15, q = l >> 4;
  const int m0 = blockIdx.x * 64;
  const int k0base = blockIdx.y * kIters * 32;

  const int srow = t >> 2;
  const int schunk = (t & 3) * 8;

  floatx4 acc[2][4];
#pragma unroll
  for (int i = 0; i < 2; ++i)
#pragma unroll
    for (int j = 0; j < 4; ++j) acc[i][j] = (floatx4)0.0f;

  for (int kb = 0; kb < kIters; ++kb) {
    const int k0 = k0base + kb * 32;
    __syncthreads();
    GLD16(A + (size_t)(m0 + srow) * lda + k0 + schunk, As + (size_t)t * 8);
    GLD16(Zh + (size_t)srow * ldz + k0 + schunk,        Zs[0] + (size_t)t * 8);
    GLD16(Zh + (size_t)(srow + 64) * ldz + k0 + schunk, Zs[0] + (size_t)(t + 256) * 8);
    GLD16(Zm + (size_t)srow * ldz + k0 + schunk,        Zs[1] + (size_t)t * 8);
    GLD16(Zm + (size_t)(srow + 64) * ldz + k0 + schunk, Zs[1] + (size_t)(t + 256) * 8);
    if (NP > 2) {
      GLD16(Zl + (size_t)srow * ldz + k0 + schunk,        Zs[2] + (size_t)t * 8);
      GLD16(Zl + (size_t)(srow + 64) * ldz + k0 + schunk, Zs[2] + (size_t)(t + 256) * 8);
    }
    __syncthreads();

    bf16x8 af[2], bz[NP][4];
#pragma unroll
    for (int mi = 0; mi < 2; ++mi)
      af[mi] = *(const bf16x8*)&As[(wr * 32 + mi * 16 + lr) * 32 + q * 8];
#pragma unroll
    for (int s = 0; s < NP; ++s)
#pragma unroll
      for (int ni = 0; ni < 4; ++ni)
        bz[s][ni] = *(const bf16x8*)&Zs[s][(wc * 64 + ni * 16 + lr) * 32 + q * 8];
#pragma unroll
    for (int s = 0; s < NP; ++s)
#pragma unroll
      for (int mi = 0; mi < 2; ++mi)
#pragma unroll
        for (int ni = 0; ni < 4; ++ni)
          acc[mi][ni] = __builtin_amdgcn_mfma_f32_16x16x32_bf16(
              af[mi], bz[s][ni], acc[mi][ni], 0, 0, 0);
  }

#pragma unroll
  for (int mi = 0; mi < 2; ++mi)
#pragma unroll
    for (int ni = 0; ni < 4; ++ni) {
      const int col = wc * 64 + ni * 16 + lr;
      const int rowb = m0 + wr * 32 + mi * 16 + q * 4;
#pragma unroll
      for (int r = 0; r < 4; ++r)
        atomicAdd(&Y[(size_t)(rowb + r) * 128 + col], acc[mi][ni][r]);
    }
}

// ---------------------------------------------------------------------------
// Aggregation M-halved (fp32 A, on-the-fly 2-plane split, diag zeroed).
// ---------------------------------------------------------------------------
template <int NP>
__global__ __launch_bounds__(256) void agg_split(
    const float* __restrict__ A, int lda,
    const bf16* __restrict__ Zh, const bf16* __restrict__ Zm, const bf16* __restrict__ Zl,
    int ldz, float* __restrict__ Y, int kIters, int aTwo)
{
  __shared__ __align__(16) bf16 Ahs[64 * 32];
  __shared__ __align__(16) bf16 Als[64 * 32];
  __shared__ __align__(16) bf16 Zs[NP][128 * 32];

  const int t = threadIdx.x;
  const int w = t >> 6, l = t & 63;
  const int wr = w >> 1, wc = w & 1;
  const int lr = l & 15, q = l >> 4;
  const int m0 = blockIdx.x * 64;
  const int k0base = blockIdx.y * kIters * 32;

  const int arow = t >> 2;           // 0..63
  const int acol = (t & 3) * 8;      // 8 floats per thread
  const int srow = t >> 2;
  const int schunk = (t & 3) * 8;

  floatx4 acc[2][4];
#pragma unroll
  for (int i = 0; i < 2; ++i)
#pragma unroll
    for (int j = 0; j < 4; ++j) acc[i][j] = (floatx4)0.0f;

  for (int kb = 0; kb < kIters; ++kb) {
    const int k0 = k0base + kb * 32;
    const float* asrc = A + (size_t)(m0 + arow) * lda + k0 + acol;
    floatx4 av[2];
#pragma unroll
    for (int i = 0; i < 2; ++i) av[i] = *(const floatx4*)(asrc + i * 4);

    __syncthreads();
    GLD16(Zh + (size_t)srow * ldz + k0 + schunk,        Zs[0] + (size_t)t * 8);
    GLD16(Zh + (size_t)(srow + 64) * ldz + k0 + schunk, Zs[0] + (size_t)(t + 256) * 8);
    GLD16(Zm + (size_t)srow * ldz + k0 + schunk,        Zs[1] + (size_t)t * 8);
    GLD16(Zm + (size_t)(srow + 64) * ldz + k0 + schunk, Zs[1] + (size_t)(t + 256) * 8);
    if (NP > 2) {
      GLD16(Zl + (size_t)srow * ldz + k0 + schunk,        Zs[2] + (size_t)t * 8);
      GLD16(Zl + (size_t)(srow + 64) * ldz + k0 + schunk, Zs[2] + (size_t)(t + 256) * 8);
    }

    bf16x4 ah[2], alo[2];
    const int grow = m0 + arow;
#pragma unroll
    for (int i = 0; i < 8; ++i) {
      float v = av[i >> 2][i & 3];
      if (k0 + acol + i == grow) v = 0.0f;
      bf16 h = (bf16)v;
      ah[i >> 2][i & 3] = h;
      alo[i >> 2][i & 3] = (bf16)(v - (float)h);
    }
    const int sbase = arow * 32 + acol;
    *(bf16x4*)&Ahs[sbase] = ah[0]; *(bf16x4*)&Ahs[sbase + 4] = ah[1];
    if (aTwo) { *(bf16x4*)&Als[sbase] = alo[0]; *(bf16x4*)&Als[sbase + 4] = alo[1]; }
    __syncthreads();

    bf16x8 afh[2], afl[2], bz[NP][4];
#pragma unroll
    for (int mi = 0; mi < 2; ++mi)
      afh[mi] = *(const bf16x8*)&Ahs[(wr * 32 + mi * 16 + lr) * 32 + q * 8];
#pragma unroll
    for (int s = 0; s < NP; ++s)
#pragma unroll
      for (int ni = 0; ni < 4; ++ni)
        bz[s][ni] = *(const bf16x8*)&Zs[s][(wc * 64 + ni * 16 + lr) * 32 + q * 8];
#pragma unroll
    for (int s = 0; s < NP; ++s)
#pragma unroll
      for (int mi = 0; mi < 2; ++mi)
#pragma unroll
        for (int ni = 0; ni < 4; ++ni)
          acc[mi][ni] = __builtin_amdgcn_mfma_f32_16x16x32_bf16(
              afh[mi], bz[s][ni], acc[mi][ni], 0, 0, 0);
    if (aTwo) {
#pragma unroll
      for (int mi = 0; mi < 2; ++mi)
        afl[mi] = *(const bf16x8*)&Als[(wr * 32 + mi * 16 + lr) * 32 + q * 8];
      constexpr int NL = (NP > 2) ? 2 : 1;
#pragma unroll
      for (int s = 0; s < NL; ++s)
#pragma unroll
        for (int mi = 0; mi < 2; ++mi)
#pragma unroll
          for (int ni = 0; ni < 4; ++ni)
            acc[mi][ni] = __builtin_amdgcn_mfma_f32_16x16x32_bf16(
                afl[mi], bz[s][ni], acc[mi][ni], 0, 0, 0);
    }
  }

#pragma unroll
  for (int mi = 0; mi < 2; ++mi)
#pragma unroll
    for (int ni = 0; ni < 4; ++ni) {
      const int col = wc * 64 + ni * 16 + lr;
      const int rowb = m0 + wr * 32 + mi * 16 + q * 4;
#pragma unroll
      for (int r = 0; r < 4; ++r)
        atomicAdd(&Y[(size_t)(rowb + r) * 128 + col], acc[mi][ni][r]);
    }
}

// ---------------------------------------------------------------------------
// Z[nr,128] = dn ⊙ (x @ W); x row = X[perm[row]]*vals[row]  (pool fusion)
//                       or  X[row] + up[inv[row]]            (unpool fusion)
// FULL=1: 6-term (2^-24), 3 planes. FULL=0: 3-term (2^-16), 2 planes.
// ---------------------------------------------------------------------------
template <int FULL>
__global__ __launch_bounds__(256) void xw_split(
    const float* __restrict__ X, const int* __restrict__ perm,
    const float* __restrict__ vals,
    const float* __restrict__ up, const int* __restrict__ inv,
    const bf16* __restrict__ Wh, const bf16* __restrict__ Wm, const bf16* __restrict__ Wl,
    const float* __restrict__ dnv, float* __restrict__ Z,
    bf16* __restrict__ Zht, bf16* __restrict__ Zmt, bf16* __restrict__ Zlt, int ldz,
    float* __restrict__ Agg, float* __restrict__ stats)
{
  __shared__ __align__(16) bf16 Xs[3][128 * 32];
  __shared__ __align__(16) bf16 Ws[3][128 * 32];

  const int t = threadIdx.x;
  if (blockIdx.x == 0) stats[t] = 0.0f;

  const int w = t >> 6, l = t & 63;
  const int wr = w >> 1, wc = w & 1;
  const int lr = l & 15, q = l >> 4;
  const int r0 = blockIdx.x * 128;

  const int srow = t >> 1;
  const int soff = (t & 1) * 16;
  const int sbase = srow * 32 + soff;

  const int row = r0 + srow;
  int grow = row;
  float scale = 1.0f;
  if (perm) { grow = perm[row]; scale = vals[row]; }
  const float* xrow = X + (size_t)grow * 128;
  const float* uprow = nullptr;
  if (up) { int j = inv[row]; if (j >= 0) uprow = up + (size_t)j * 128; }

  floatx4 acc[4][4];
#pragma unroll
  for (int i = 0; i < 4; ++i)
#pragma unroll
    for (int j = 0; j < 4; ++j) acc[i][j] = (floatx4)0.0f;

  const bf16* wsrc[3] = {Wh, Wm, Wl};

  for (int ks = 0; ks < 4; ++ks) {
    const int k0 = ks * 32;
    float xv[16];
#pragma unroll
    for (int i = 0; i < 16; i += 4) {
      floatx4 tmp = *(const floatx4*)(xrow + k0 + soff + i);
      if (uprow) {
        floatx4 u = *(const floatx4*)(uprow + k0 + soff + i);
        tmp += u;
      }
      xv[i] = tmp[0] * scale; xv[i + 1] = tmp[1] * scale;
      xv[i + 2] = tmp[2] * scale; xv[i + 3] = tmp[3] * scale;
    }
    bf16x8 wv[3][2];
#pragma unroll
    for (int s = 0; s < 3; ++s) {
      const bf16* ws = wsrc[s] + (size_t)srow * 128 + k0 + soff;
      wv[s][0] = *(const bf16x8*)ws;
      wv[s][1] = *(const bf16x8*)(ws + 8);
    }
    bf16x8 vh[2], vm[2], vl[2];
#pragma unroll
    for (int i = 0; i < 16; ++i) {
      float v = xv[i];
      bf16 h = (bf16)v; float r1 = v - (float)h;
      bf16 m = (bf16)r1; float r2 = r1 - (float)m;
      vh[i >> 3][i & 7] = h; vm[i >> 3][i & 7] = m; vl[i >> 3][i & 7] = (bf16)r2;
    }
    __syncthreads();
    *(bf16x8*)&Xs[0][sbase] = vh[0]; *(bf16x8*)&Xs[0][sbase + 8] = vh[1];
    *(bf16x8*)&Xs[1][sbase] = vm[0]; *(bf16x8*)&Xs[1][sbase + 8] = vm[1];
    *(bf16x8*)&Xs[2][sbase] = vl[0]; *(bf16x8*)&Xs[2][sbase + 8] = vl[1];
#pragma unroll
    for (int s = 0; s < 3; ++s) {
      *(bf16x8*)&Ws[s][sbase] = wv[s][0];
      *(bf16x8*)&Ws[s][sbase + 8] = wv[s][1];
    }
    __syncthreads();

    bf16x8 af[3][4], bfg[3][4];
#pragma unroll
    for (int s = 0; s < 3; ++s) {
#pragma unroll
      for (int mi = 0; mi < 4; ++mi)
        af[s][mi] = *(const bf16x8*)&Xs[s][(wr * 64 + mi * 16 + lr) * 32 + q * 8];
#pragma unroll
      for (int ni = 0; ni < 4; ++ni)
        bfg[s][ni] = *(const bf16x8*)&Ws[s][(wc * 64 + ni * 16 + lr) * 32 + q * 8];
    }
    constexpr int NT = FULL ? 6 : 3;
    constexpr int sa[6] = {0, 0, 1, 1, 0, 2};
    constexpr int sb[6] = {0, 1, 0, 1, 2, 0};
#pragma unroll
    for (int p = 0; p < NT; ++p)
#pragma unroll
      for (int mi = 0; mi < 4; ++mi)
#pragma unroll
        for (int ni = 0; ni < 4; ++ni)
          acc[mi][ni] = __builtin_amdgcn_mfma_f32_16x16x32_bf16(
              af[sa[p]][mi], bfg[sb[p]][ni], acc[mi][ni], 0, 0, 0);
  }

#pragma unroll
  for (int mi = 0; mi < 4; ++mi) {
    const int rowb = r0 + wr * 64 + mi * 16 + q * 4;
    float dnr[4];
#pragma unroll
    for (int r = 0; r < 4; ++r) dnr[r] = dnv[rowb + r];
#pragma unroll
    for (int ni = 0; ni < 4; ++ni) {
      const int col = wc * 64 + ni * 16 + lr;
      bf16x4 h4, m4, l4;
#pragma unroll
      for (int r = 0; r < 4; ++r) {
        float v = dnr[r] * acc[mi][ni][r];
        Z[(size_t)(rowb + r) * 128 + col] = v;
        Agg[(size_t)(rowb + r) * 128 + col] = 0.0f;
        bf16 h = (bf16)v; float r1 = v - (float)h;
        bf16 m = (bf16)r1; float r2 = r1 - (float)m;
        h4[r] = h; m4[r] = m; l4[r] = (bf16)r2;
      }
      *(bf16x4*)&Zht[(size_t)col * ldz + rowb] = h4;
      *(bf16x4*)&Zmt[(size_t)col * ldz + rowb] = m4;
      if (FULL) *(bf16x4*)&Zlt[(size_t)col * ldz + rowb] = l4;
    }
  }
}

// ---------------------------------------------------------------------------
// Fused prep: blocks [0,4096) adj->bf16+dn; [4096,4544) conv_w 3-way split;
// block 4544 pool_w inverse norms.
// ---------------------------------------------------------------------------
__global__ void prep_all(const float* __restrict__ adj, bf16* __restrict__ ah,
                         float* __restrict__ dn, int n,
                         const float* __restrict__ W, bf16* __restrict__ Wh,
                         bf16* __restrict__ Wm, bf16* __restrict__ Wl,
                         const float* __restrict__ pw, float* __restrict__ invp) {
  const int bid = blockIdx.x;
  const int t = threadIdx.x;
  if (bid < 4096) {
    int r = bid;
    const float* arow = adj + (size_t)r * n;
    bf16* orow = ah + (size_t)r * n;
    float sum = 0.f;
    for (int c4 = t * 4; c4 < n; c4 += 1024) {
      floatx4 v = *(const floatx4*)(arow + c4);
      bf16x4 o;
#pragma unroll
      for (int e = 0; e < 4; ++e) {
        float x = (c4 + e == r) ? 0.0f : v[e];
        sum += x; o[e] = (bf16)x;
      }
      *(bf16x4*)&orow[c4] = o;
    }
    __shared__ float red[256];
    red[t] = sum; __syncthreads();
    for (int off = 128; off; off >>= 1) {
      if (t < off) red[t] += red[t + off];
      __syncthreads();
    }
    if (t == 0) dn[r] = 1.0f / sqrtf(red[0] + 2.0f);
  } else if (bid < 4544) {
    int idx = (bid - 4096) * 256 + t;
    int l = idx >> 14, rem = idx & 16383, c = rem >> 7, k = rem & 127;
    float v = W[(l << 14) + (k << 7) + c];
    bf16 h = (bf16)v; float r1 = v - (float)h;
    bf16 m = (bf16)r1; float r2 = r1 - (float)m;
    Wh[idx] = h; Wm[idx] = m; Wl[idx] = (bf16)r2;
  } else {
    __shared__ float red[128];
    if (t < 128) {
      for (int l = 0; l < 3; ++l) {
        float v = pw[l * 128 + t];
        red[t] = v * v; __syncthreads();
        for (int off = 64; off; off >>= 1) {
          if (t < off) red[t] += red[t + off];
          __syncthreads();
        }
        if (t == 0) invp[l] = 1.0f / sqrtf(red[0]);
        __syncthreads();
      }
    }
  }
}

__global__ void dn_rows_bf(const bf16* __restrict__ A, int lda, float* __restrict__ dn,
                           int n) {
  int r = blockIdx.x, t = threadIdx.x;
  const bf16* row = A + (size_t)r * lda;
  float sum = 0.f;
  for (int c4 = t * 4; c4 < n; c4 += 1024) {
    bf16x4 v = *(const bf16x4*)&row[c4];
#pragma unroll
    for (int e = 0; e < 4; ++e) sum += (float)v[e];
  }
  __shared__ float red[256];
  red[t] = sum; __syncthreads();
  for (int off = 128; off; off >>= 1) {
    if (t < off) red[t] += red[t + off];
    __syncthreads();
  }
  if (t == 0) dn[r] = 1.0f / sqrtf(red[0] + 2.0f);
}

__global__ void dn_rows(const float* __restrict__ A, int lda, float* __restrict__ dn,
                        int n) {
  int r = blockIdx.x, t = threadIdx.x;
  const float* row = A + (size_t)r * lda;
  float sum = 0.f;
  for (int c = t; c < n; c += 256)
    if (c != r) sum += row[c];
  __shared__ float red[256];
  red[t] = sum; __syncthreads();
  for (int off = 128; off; off >>= 1) {
    if (t < off) red[t] += red[t + off];
    __syncthreads();
  }
  if (t == 0) dn[r] = 1.0f / sqrtf(red[0] + 2.0f);
}

// ---------------------------------------------------------------------------
// Fused top-k select: radix k-th largest (snapshot-fixed) + deterministic
// compaction (+inverse perm) in one single-block kernel.
// ---------------------------------------------------------------------------
__device__ inline unsigned f2u(float f) {
  unsigned u = __float_as_uint(f);
  return (u & 0x80000000u) ? ~u : (u | 0x80000000u);
}
__global__ __launch_bounds__(1024) void select_kernel(
    const float* __restrict__ s, int n, int k,
    int* __restrict__ perm, float* __restrict__ vals, int* __restrict__ inv)
{
  __shared__ int hist[256];
  __shared__ int suf[256];
  __shared__ unsigned sh_prefix;
  __shared__ int sh_krem;
  __shared__ float sh_thr;
  __shared__ int cg[1024], ce[1024];
  const int t = threadIdx.x;
  if (t == 0) { sh_prefix = 0; sh_krem = k; }

  for (int round = 0; round < 4; ++round) {
    const int shift = 24 - 8 * round;
    if (t < 256) hist[t] = 0;
    __syncthreads();
    const unsigned pref = sh_prefix;
    const int krem = sh_krem;
    for (int i = t; i < n; i += 1024) {
      unsigned u = f2u(s[i]);
      if (round == 0 || (u >> (shift + 8)) == pref)
        atomicAdd(&hist[(u >> shift) & 255], 1);
    }
    __syncthreads();
    if (t < 256) suf[t] = hist[255 - t];
    __syncthreads();
    for (int off = 1; off < 256; off <<= 1) {
      int v = (t < 256 && t >= off) ? suf[t - off] : 0;
      __syncthreads();
      if (t < 256) suf[t] += v;
      __syncthreads();
    }
    if (t < 256) {
      int prev = (t == 0) ? 0 : suf[t - 1];
      if (suf[t] >= krem && prev < krem) {
        sh_prefix = (pref << 8) | (unsigned)(255 - t);
        sh_krem = krem - prev;
      }
    }
    __syncthreads();
  }
  if (t == 0) {
    unsigned u = sh_prefix;
    sh_thr = (u & 0x80000000u) ? __uint_as_float(u & 0x7fffffffu)
                               : __uint_as_float(~u);
  }
  for (int i = t; i < n; i += 1024) inv[i] = -1;
  __syncthreads();

  const float thr = sh_thr;
  const int chunk = n >> 10;
  const int beg = t * chunk;
  int g = 0, e = 0;
  for (int i = 0; i < chunk; ++i) {
    float v = s[beg + i];
    g += (v > thr); e += (v == thr);
  }
  cg[t] = g; ce[t] = e; __syncthreads();
  for (int off = 1; off < 1024; off <<= 1) {
    int a = (t >= off) ? cg[t - off] : 0;
    int b = (t >= off) ? ce[t - off] : 0;
    __syncthreads();
    cg[t] += a; ce[t] += b;
    __syncthreads();
  }
  const int total_gt = cg[1023];
  int pg = cg[t] - g;
  int pe = ce[t] - e;
  const int need = k - total_gt;
  for (int i = 0; i < chunk; ++i) {
    float v = s[beg + i];
    if (v > thr) {
      if (pg < k) { perm[pg] = beg + i; vals[pg] = v; inv[beg + i] = pg; }
      ++pg;
    } else if (v == thr) {
      if (pe < need && total_gt + pe < k) {
        perm[total_gt + pe] = beg + i; vals[total_gt + pe] = v;
        inv[beg + i] = total_gt + pe;
      }
      ++pe;
    }
  }
}

__global__ void gather_bf(const bf16* __restrict__ src, int lda,
                          const int* __restrict__ perm, bf16* __restrict__ R, int n) {
  int j = blockIdx.x, t = threadIdx.x;
  int r = perm[j];
  const bf16* s = src + (size_t)r * lda;
  bf16* o = R + (size_t)j * n;
  for (int c4 = t * 4; c4 < n; c4 += 1024) {
    bf16x4 v = *(const bf16x4*)&s[c4];
    if (r >= c4 && r < c4 + 4) v[r - c4] = (bf16)1.0f;
    *(bf16x4*)&o[c4] = v;
  }
}

__global__ void gather_f32(const float* __restrict__ src, int lda,
                           const int* __restrict__ perm, bf16* __restrict__ R, int n) {
  int j = blockIdx.x, t = threadIdx.x;
  int r = perm[j];
  const float* s = src + (size_t)r * lda;
  bf16* o = R + (size_t)j * n;
  for (int c4 = t * 4; c4 < n; c4 += 1024) {
    floatx4 v = *(const floatx4*)(s + c4);
    bf16x4 ob;
#pragma unroll
    for (int e = 0; e < 4; ++e)
      ob[e] = (c4 + e == r) ? (bf16)1.0f : (bf16)v[e];
    *(bf16x4*)&o[c4] = ob;
  }
}

// y = dn[r]*(Agg + 2*Z) + bias; relu?; write Agg in-place; BN col stats.
__global__ void gcn_post(float* __restrict__ acc, const float* __restrict__ Zf,
                         const float* __restrict__ dn, const float* __restrict__ bias,
                         float* __restrict__ stats, int relu) {
  int c = threadIdx.x;
  int r0 = blockIdx.x * 16;
  float b = bias[c];
  float s = 0.f, qq = 0.f;
  for (int i = 0; i < 16; ++i) {
    int r = r0 + i;
    float v = dn[r] * (acc[(size_t)r * 128 + c] + 2.0f * Zf[(size_t)r * 128 + c]) + b;
    if (relu) v = fmaxf(v, 0.f);
    acc[(size_t)r * 128 + c] = v;
    s += v; qq += v * v;
  }
  atomicAdd(&stats[c], s);
  atomicAdd(&stats[128 + c], qq);
}

// BN apply (coef recomputed per block) + optional fused pooling score.
__global__ void bn_apply(const float* __restrict__ H, const float* __restrict__ stats,
                         const float* __restrict__ g, const float* __restrict__ b,
                         int n, float* __restrict__ xout,
                         const float* __restrict__ pw, const float* __restrict__ invp,
                         float* __restrict__ scores) {
  int r = blockIdx.x, c = threadIdx.x;
  float m = stats[c] / n;
  float var = stats[128 + c] / n - m * m;
  float sc = g[c] / sqrtf(var + 1e-5f);
  float off = b[c] - m * sc;
  float v = sc * H[(size_t)r * 128 + c] + off;
  xout[(size_t)r * 128 + c] = v;
  if (pw) {
    __shared__ float red[128];
    red[c] = v * pw[c]; __syncthreads();
    for (int o = 64; o; o >>= 1) {
      if (c < o) red[c] += red[c + o];
      __syncthreads();
    }
    if (c == 0) scores[r] = tanhf(red[0] * invp[0]);
  }
}

// ---------------------------------------------------------------------------
extern "C" void kernel_launch(void* const* d_in, const int* in_sizes, int n_in,
                              void* d_out, int out_size, void* d_ws, size_t ws_size,
                              hipStream_t stream) {
  const float* x_in   = (const float*)d_in[0];
  const float* adj    = (const float*)d_in[1];
  const float* conv_w = (const float*)d_in[2];
  const float* conv_b = (const float*)d_in[3];
  const float* pool_w = (const float*)d_in[4];
  const float* bn_g   = (const float*)d_in[5];
  const float* bn_b   = (const float*)d_in[6];
  float* out = (float*)d_out;
  (void)in_sizes; (void)n_in; (void)out_size; (void)ws_size;

  char* p = (char*)d_ws;
  auto alloc = [&](size_t bytes) -> void* {
    void* r = (void*)p;
    p += (bytes + 255) & ~(size_t)255;
    return r;
  };
  bf16*  Ah0bf = (bf16*)alloc(4096ull * 4096 * 2);
  bf16*  A1bf  = (bf16*)alloc(2048ull * 2048 * 2);
  float* A2f   = (float*)alloc(1024ull * 1024 * 4);
  float* A3f   = (float*)alloc(512ull * 512 * 4);
  bf16*  Rbuf  = (bf16*)alloc(2048ull * 4096 * 2);
  void*  Cs    = alloc(136ull * 4 * 16384 * 4);   // L1 bf16 (17.8MB) / L2,L3 fp32
  float* Z     = (float*)alloc(4096ull * 128 * 4);
  bf16*  Zht   = (bf16*)alloc(128ull * 4096 * 2);
  bf16*  Zmt   = (bf16*)alloc(128ull * 4096 * 2);
  bf16*  Zlt   = (bf16*)alloc(128ull * 4096 * 2);
  float* Agg   = (float*)alloc(4096ull * 128 * 4);
  float* res0  = (float*)alloc(4096ull * 128 * 4);
  float* res1  = (float*)alloc(2048ull * 128 * 4);
  float* res2  = (float*)alloc(1024ull * 128 * 4);
  float* xb0   = (float*)alloc(512ull * 128 * 4);
  float* xb1   = (float*)alloc(1024ull * 128 * 4);
  float* xb2   = (float*)alloc(2048ull * 128 * 4);
  bf16*  Wh    = (bf16*)alloc(7ull * 16384 * 2);
  bf16*  Wm    = (bf16*)alloc(7ull * 16384 * 2);
  bf16*  Wl    = (bf16*)alloc(7ull * 16384 * 2);
  float* scores = (float*)alloc(4096 * 4);
  int*   perm0 = (int*)alloc(2048 * 4);
  int*   perm1 = (int*)alloc(1024 * 4);
  int*   perm2 = (int*)alloc(512 * 4);
  int*   inv0  = (int*)alloc(4096 * 4);
  int*   inv1  = (int*)alloc(2048 * 4);
  int*   inv2  = (int*)alloc(1024 * 4);
  float* vals0 = (float*)alloc(2048 * 4);
  float* vals1 = (float*)alloc(1024 * 4);
  float* vals2 = (float*)alloc(512 * 4);
  float* dn0   = (float*)alloc(4096 * 4);
  float* dn1   = (float*)alloc(2048 * 4);
  float* dn2   = (float*)alloc(1024 * 4);
  float* dn3   = (float*)alloc(512 * 4);
  float* invp  = (float*)alloc(256);
  float* stats = (float*)alloc(1024);

  auto gcn = [&](int nr, const bf16* Abf, const float* Af32, const float* dnv,
                 int layer, const float* xsrc, const int* perm, const float* vals,
                 const float* up, const int* inv, float* xout, int relu, int aTwo,
                 const float* pw, const float* ip, int full) {
    if (full)
      xw_split<1><<<nr / 128, 256, 0, stream>>>(
          xsrc, perm, vals, up, inv,
          Wh + layer * 16384, Wm + layer * 16384, Wl + layer * 16384, dnv,
          Z, Zht, Zmt, Zlt, nr, Agg, stats);
    else
      xw_split<0><<<nr / 128, 256, 0, stream>>>(
          xsrc, perm, vals, up, inv,
          Wh + layer * 16384, Wm + layer * 16384, Wl + layer * 16384, dnv,
          Z, Zht, Zmt, Zlt, nr, Agg, stats);
    if (Abf) {
      if (full)
        agg_bf<3><<<dim3(nr / 64, 8), 256, 0, stream>>>(
            Abf, nr, Zht, Zmt, Zlt, nr, Agg, nr / 256);
      else
        agg_bf<2><<<dim3(nr / 64, 8), 256, 0, stream>>>(
            Abf, nr, Zht, Zmt, Zlt, nr, Agg, nr / 256);
    } else {
      if (full)
        agg_split<3><<<dim3(nr / 64, 8), 256, 0, stream>>>(
            Af32, nr, Zht, Zmt, Zlt, nr, Agg, nr / 256, aTwo);
      else
        agg_split<2><<<dim3(nr / 64, 8), 256, 0, stream>>>(
            Af32, nr, Zht, Zmt, Zlt, nr, Agg, nr / 256, aTwo);
    }
    gcn_post<<<nr / 16, 128, 0, stream>>>(Agg, Z, dnv, conv_b + layer * 128, stats, relu);
    bn_apply<<<nr, 128, 0, stream>>>(Agg, stats, bn_g + layer * 128, bn_b + layer * 128,
                                     nr, xout, pw, ip, scores);
  };

  // Pool: fused select -> gather R=(A+I)[perm] -> M-halved R R^T (slices, no
  // atomics; bf16 slices at L1 where partials are exact ints) -> sym_post -> dn.
  auto pool = [&](int n, const bf16* srcBf, const float* srcF32,
                  bf16* outBf, float* outF32, float* dnNew,
                  int* perm, float* vals, int* inv, int splitZ, int sliceBf) {
    int k = n / 2, G = k / 128, pairs = G * (G + 1) / 2;
    select_kernel<<<1, 1024, 0, stream>>>(scores, n, k, perm, vals, inv);
    if (srcBf) gather_bf<<<k, 256, 0, stream>>>(srcBf, n, perm, Rbuf, n);
    else       gather_f32<<<k, 256, 0, stream>>>(srcF32, n, perm, Rbuf, n);
    gemm_sym<<<dim3(pairs * 2, splitZ), 256, 0, stream>>>(
        Rbuf, sliceBf ? (bf16*)Cs : nullptr, sliceBf ? nullptr : (float*)Cs,
        n, n / (splitZ * 32), G, pairs);
    sym_post<<<pairs, 128, 0, stream>>>(
        sliceBf ? (const bf16*)Cs : nullptr, sliceBf ? nullptr : (const float*)Cs,
        outBf, outF32, k, G, pairs, splitZ);
    if (outBf) dn_rows_bf<<<k, 256, 0, stream>>>(outBf, k, dnNew, k);
    else       dn_rows<<<k, 256, 0, stream>>>(outF32, k, dnNew, k);
  };

  // ---- prep (one launch) ----
  prep_all<<<4545, 256, 0, stream>>>(adj, Ah0bf, dn0, 4096,
                                     conv_w, Wh, Wm, Wl, pool_w, invp);

  // ---- down ---- (layers 0-2 feed top-k selections: full precision)
  gcn(4096, Ah0bf, nullptr, dn0, 0, x_in, nullptr, nullptr, nullptr, nullptr,
      res0, 1, 0, pool_w + 0, invp + 0, 1);
  pool(4096, Ah0bf, nullptr, A1bf, nullptr, dn1, perm0, vals0, inv0, 4, 1);
  gcn(2048, A1bf, nullptr, dn1, 1, res0, perm0, vals0, nullptr, nullptr,
      res1, 1, 0, pool_w + 128, invp + 1, 1);
  pool(2048, A1bf, nullptr, nullptr, A2f, dn2, perm1, vals1, inv1, 4, 0);
  gcn(1024, nullptr, A2f, dn2, 2, res1, perm1, vals1, nullptr, nullptr,
      res2, 1, 1, pool_w + 256, invp + 2, 1);
  pool(1024, nullptr, A2f, nullptr, A3f, dn3, perm2, vals2, inv2, 8, 0);
  // ---- layers 3-6 are value-path only: trimmed precision ----
  gcn(512, nullptr, A3f, dn3, 3, res2, perm2, vals2, nullptr, nullptr,
      xb0, 1, 1, nullptr, nullptr, 0);

  // ---- up ---- (unpool add fused into xw_split; res buffers stay intact)
  gcn(1024, nullptr, A2f, dn2, 4, res2, nullptr, nullptr, xb0, inv2,
      xb1, 1, 1, nullptr, nullptr, 0);
  gcn(2048, A1bf, nullptr, dn1, 5, res1, nullptr, nullptr, xb1, inv1,
      xb2, 1, 0, nullptr, nullptr, 0);
  gcn(4096, Ah0bf, nullptr, dn0, 6, res0, nullptr, nullptr, xb2, inv0,
      out, 0, 0, nullptr, nullptr, 0);
}